// Round 1
// baseline (3422.866 us; speedup 1.0000x reference)
//
#include <hip/hip_runtime.h>
#include <math.h>

#define S_ 16
#define M_ 256
#define NF_ 4096
#define OUT_ 256
#define ROWS_ (M_ + NF_)     // 4352
#define JITTER_ 1e-8f
#define MM_ (M_ * M_)        // 65536

// ---------------- small prep kernels ----------------

__global__ void max1_kernel(const float* __restrict__ x, int n, float* part) {
    __shared__ float red[256];
    int tid = threadIdx.x;
    float m = -3.4e38f;
    for (int i = blockIdx.x * blockDim.x + tid; i < n; i += gridDim.x * blockDim.x)
        m = fmaxf(m, x[i]);
    red[tid] = m; __syncthreads();
    for (int s = 128; s > 0; s >>= 1) {
        if (tid < s) red[tid] = fmaxf(red[tid], red[tid + s]);
        __syncthreads();
    }
    if (tid == 0) part[blockIdx.x] = red[0];
}

__global__ void max2_kernel(const float* part, float* ws) {
    __shared__ float red[256];
    int tid = threadIdx.x;
    red[tid] = part[tid]; __syncthreads();
    for (int s = 128; s > 0; s >>= 1) {
        if (tid < s) red[tid] = fmaxf(red[tid], red[tid + s]);
        __syncthreads();
    }
    if (tid == 0) { ws[0] = red[0]; ws[2] = JITTER_ * red[0]; }
}

__global__ void prep_kernel(const float* __restrict__ Lloc, const float* __restrict__ Lscale, float* ws) {
    __shared__ float red[256];
    int tid = threadIdx.x;
    red[tid] = Lloc[tid * M_ + tid];
    __syncthreads();
    for (int s = 128; s > 0; s >>= 1) {
        if (tid < s) red[tid] += red[tid + s];
        __syncthreads();
    }
    if (tid == 0) {
        float norm = red[0] / (float)M_;
        ws[1] = expf(Lscale[0]) / norm;
    }
}

__global__ void scaleL_kernel(const float* __restrict__ Lloc, const float* __restrict__ ws, float* __restrict__ L) {
    int i = blockIdx.x * blockDim.x + threadIdx.x;
    if (i < MM_) L[i] = Lloc[i] * ws[1];
}

__global__ void copyjit_kernel(const float* __restrict__ Kuu, const float* __restrict__ ws, float* __restrict__ dst) {
    int i = blockIdx.x * blockDim.x + threadIdx.x;
    if (i < S_ * MM_) {
        float v = Kuu[i];
        int r = (i >> 8) & 255;
        int c = i & 255;
        if (r == c) v += ws[2];
        dst[i] = v;
    }
}

// ---------------- batched Cholesky (packed lower triangle in LDS) ----------------
// LDL-style elimination (one sync per column), scale to L = chol lower on writeback.

__global__ __launch_bounds__(256) void chol_kernel(float* bufA, float* bufB) {
    int blk = blockIdx.x;                       // 0..31
    float* Ag = (blk < S_) ? (bufA + (long)blk * MM_) : (bufB + (long)(blk - S_) * MM_);
    __shared__ float P[M_ * (M_ + 1) / 2];      // 32896 floats = 131.6 KB
    int tid = threadIdx.x;
    for (int i = 0; i < M_; i++) {
        int base = i * (i + 1) / 2;
        for (int j = tid; j <= i; j += 256) P[base + j] = Ag[i * M_ + j];
    }
    __syncthreads();
    for (int k = 0; k < M_; k++) {
        float rd = 1.0f / P[(k * (k + 1) / 2) + k];
        int n = M_ - 1 - k;
        int total = n * (n + 1) / 2;
        int t = tid;
        if (t < total) {
            int a = (int)((sqrtf(8.0f * (float)t + 1.0f) - 1.0f) * 0.5f);
            while ((a + 1) * (a + 2) / 2 <= t) a++;
            while (a * (a + 1) / 2 > t) a--;
            int b = t - a * (a + 1) / 2;
            while (t < total) {
                int i = k + 1 + a, j = k + 1 + b;
                P[i * (i + 1) / 2 + j] -= P[i * (i + 1) / 2 + k] * (P[j * (j + 1) / 2 + k] * rd);
                t += 256; b += 256;
                while (b > a) { b -= (a + 1); a++; }
            }
        }
        __syncthreads();
    }
    // writeback lower triangle scaled to true Cholesky factor
    for (int i = 0; i < M_; i++) {
        int base = i * (i + 1) / 2;
        for (int j = tid; j <= i; j += 256) {
            float d = P[j * (j + 1) / 2 + j];
            Ag[i * M_ + j] = P[base + j] / sqrtf(d);
        }
    }
}

// ---------------- batched lower-triangular inverse ----------------
// Columns are independent solves L x = e_j. Block handles 64 columns (j = 4c+cb),
// 4 threads per column each owning a 64-row quarter of the accumulator (in LDS).

__global__ __launch_bounds__(256) void trinv_kernel(const float* bufA, const float* bufB,
                                                    float* TA_, float* TB_) {
    int mat = blockIdx.y;      // 0..31
    int cb  = blockIdx.x;      // 0..3
    const float* Lg = (mat < S_) ? (bufA + (long)mat * MM_) : (bufB + (long)(mat - S_) * MM_);
    float* Tg       = (mat < S_) ? (TA_ + (long)mat * MM_) : (TB_ + (long)(mat - S_) * MM_);
    __shared__ float X[M_ * 65];    // [k][c], stride 65 to spread banks
    __shared__ float diag[M_];
    int tid = threadIdx.x;
    int c = tid >> 2;          // 0..63
    int q = tid & 3;           // 0..3
    int j = (c << 2) | cb;     // this thread-group's column
    for (int i = tid; i < M_ * 65; i += 256) X[i] = 0.f;
    for (int i = tid; i < M_; i += 256) diag[i] = Lg[i * M_ + i];
    __syncthreads();
    for (int t = 0; t < M_; t++) {
        if (q == (t >> 6)) {
            float x = 0.f;
            if (j <= t) {
                float acc = X[t * 65 + c];
                x = (((t == j) ? 1.0f : 0.0f) - acc) / diag[t];
                X[t * 65 + c] = x;
            }
            Tg[t * M_ + j] = x;   // also zeroes the upper triangle
        }
        __syncthreads();
        if (j <= t) {
            float x = X[t * 65 + c];
            int kend = (q << 6) + 64;
            int kbeg = (q << 6);
            if (kbeg < t + 1) kbeg = t + 1;
            for (int k = kbeg; k < kend; k++) {
                X[k * 65 + c] += Lg[k * M_ + t] * x;
            }
        }
        // no second sync needed: slot (t+1) is owned by the same thread that reads it next
    }
}

// ---------------- generic tiled fp32 GEMM ----------------
// C = alpha*opA(A)@opB(B) [+ C if ACC] [+ dcoef*D] [+ I if addI]
// [+ vf[row]*noise[row*256+col] if EF]    (vf holds sqrt(Vf))

struct GemmParams {
    const float* A; const float* B; float* C;
    const float* D;
    const float* vf; const float* noise;
    int M, N, K;
    int lda, ldb, ldc;
    long sA, sB, sC, sD;
    float alpha, dcoef;
    int addI;
    long sVf, sNoise;
};

template<int TAf, int TBf, int ACCf, int EFf>
__global__ __launch_bounds__(256) void gemm_k(GemmParams p) {
    int bz = blockIdx.z;
    const float* A = p.A + (long)bz * p.sA;
    const float* B = p.B + (long)bz * p.sB;
    float* C = p.C + (long)bz * p.sC;
    int bm = blockIdx.y * 64, bn = blockIdx.x * 64;
    __shared__ float As[16][68];
    __shared__ float Bs[16][68];
    int tid = threadIdx.x;
    int tx = tid & 15, ty = tid >> 4;
    float acc[4][4] = {};
    for (int k0 = 0; k0 < p.K; k0 += 16) {
        if (TAf) {            // opA(i,k) = A[k*lda+i]  -> contiguous in i
            int i = tid & 63, kk0 = tid >> 6;
            #pragma unroll
            for (int r = 0; r < 4; r++) {
                int kk = kk0 + r * 4;
                As[kk][i] = A[(long)(k0 + kk) * p.lda + bm + i];
            }
        } else {              // opA(i,k) = A[i*lda+k]  -> contiguous in k
            int kk = tid & 15, i0 = tid >> 4;
            #pragma unroll
            for (int r = 0; r < 4; r++) {
                int i = i0 + r * 16;
                As[kk][i] = A[(long)(bm + i) * p.lda + k0 + kk];
            }
        }
        if (TBf) {            // opB(k,j) = B[j*ldb+k]  -> contiguous in k
            int kk = tid & 15, j0 = tid >> 4;
            #pragma unroll
            for (int r = 0; r < 4; r++) {
                int jj = j0 + r * 16;
                Bs[kk][jj] = B[(long)(bn + jj) * p.ldb + k0 + kk];
            }
        } else {              // opB(k,j) = B[k*ldb+j]  -> contiguous in j
            int jj = tid & 63, kk0 = tid >> 6;
            #pragma unroll
            for (int r = 0; r < 4; r++) {
                int kk = kk0 + r * 4;
                Bs[kk][jj] = B[(long)(k0 + kk) * p.ldb + bn + jj];
            }
        }
        __syncthreads();
        #pragma unroll
        for (int kk = 0; kk < 16; kk++) {
            float a[4], b4[4];
            #pragma unroll
            for (int u = 0; u < 4; u++) a[u] = As[kk][(ty << 2) + u];
            #pragma unroll
            for (int v = 0; v < 4; v++) b4[v] = Bs[kk][(tx << 2) + v];
            #pragma unroll
            for (int u = 0; u < 4; u++)
                #pragma unroll
                for (int v = 0; v < 4; v++)
                    acc[u][v] = fmaf(a[u], b4[v], acc[u][v]);
        }
        __syncthreads();
    }
    #pragma unroll
    for (int u = 0; u < 4; u++) {
        int row = bm + (ty << 2) + u;
        float4 outv;
        float* o = (float*)&outv;
        #pragma unroll
        for (int v = 0; v < 4; v++) {
            int col = bn + (tx << 2) + v;
            float val = p.alpha * acc[u][v];
            if (ACCf) val += C[(long)row * p.ldc + col];
            if (p.D)  val += p.dcoef * p.D[(long)bz * p.sD + (long)row * p.ldc + col];
            if (p.addI && row == col) val += 1.0f;
            if (EFf)  val += p.vf[(long)bz * p.sVf + row] *
                             p.noise[(long)bz * p.sNoise + (long)row * 256 + col];
            o[v] = val;
        }
        *(float4*)&C[(long)row * p.ldc + bn + (tx << 2)] = outv;
    }
}

// ---------------- Vf = sqrt(Kff_diag - sum_m A*Kuf) ----------------

__global__ void vf_kernel(const float* __restrict__ Achunk, const float* __restrict__ Kuf,
                          const float* __restrict__ Kff, float* __restrict__ Vf,
                          int f0, int nfc) {
    int s = blockIdx.y;
    int fl = blockIdx.x * 256 + threadIdx.x;
    if (fl >= nfc) return;
    const float* Ab = Achunk + (long)s * M_ * nfc;
    const float* Kb = Kuf + (long)s * M_ * NF_ + f0;
    float acc = 0.f;
    for (int m = 0; m < M_; m++)
        acc += Ab[(long)m * nfc + fl] * Kb[(long)m * NF_ + fl];
    float v = Kff[(long)s * NF_ + f0 + fl] - acc;
    Vf[(long)s * NF_ + f0 + fl] = sqrtf(v);
}

__global__ void ucopy_kernel(const float* __restrict__ U, float* __restrict__ out) {
    int i = blockIdx.x * blockDim.x + threadIdx.x;
    if (i < S_ * M_ * OUT_) {
        int s = i >> 16;
        int rc = i & 65535;
        out[(long)s * ROWS_ * OUT_ + rc] = U[i];
    }
}

// ---------------- host ----------------

extern "C" void kernel_launch(void* const* d_in, const int* in_sizes, int n_in,
                              void* d_out, int out_size, void* d_ws, size_t ws_size,
                              hipStream_t stream) {
    const float* Kuu       = (const float*)d_in[0];
    const float* Kuf       = (const float*)d_in[1];
    const float* Kff       = (const float*)d_in[2];
    const float* Lloc      = (const float*)d_in[3];
    const float* Lscale    = (const float*)d_in[4];
    const float* u_param   = (const float*)d_in[5];
    const float* noise_inv = (const float*)d_in[6];
    const float* noise_L   = (const float*)d_in[7];
    const float* noise_f   = (const float*)d_in[8];
    float* out = (float*)d_out;
    float* ws  = (float*)d_ws;

    long off = 1024;
    float* part   = ws + 16;
    float* Lbuf   = ws + off; off += MM_;
    float* UPt    = ws + off; off += MM_;
    float* UP     = ws + off; off += MM_;
    float* Vf     = ws + off; off += (long)S_ * NF_;
    float* cholK  = ws + off; off += (long)S_ * MM_;
    float* TK     = ws + off; off += (long)S_ * MM_;
    float* KuuL   = ws + off; off += (long)S_ * MM_;
    float* choll  = ws + off; off += (long)S_ * MM_;
    float* Tl     = ws + off; off += (long)S_ * MM_;
    float* KuuInv = ws + off; off += (long)S_ * MM_;
    float* lKlpIi = ws + off; off += (long)S_ * MM_;
    float* Stmp   = ws + off; off += (long)S_ * MM_;
    float* Sigma  = ws + off; off += (long)S_ * MM_;
    float* RHS    = ws + off; off += (long)S_ * MM_;
    float* U      = ws + off; off += (long)S_ * MM_;
    float* Achunk = ws + off;
    long avail = (long)(ws_size / 4) - off;
    int nfc = (int)(avail / ((long)S_ * M_));
    nfc = (nfc / 64) * 64;
    if (nfc > NF_) nfc = NF_;
    if (nfc < 64) nfc = 64;

    dim3 b256(256);

    auto run = [&](const float* A, const float* B, float* C,
                   int Mm, int Nn, int Kk, int lda, int ldb, int ldc,
                   long sA, long sB, long sC,
                   int TAf, int TBf, int ACCf, float alpha,
                   const float* D, long sD, float dcoef, int addI,
                   const float* vfp, long sVf, const float* noisep, long sNoise, int EFf,
                   int batch) {
        GemmParams q;
        q.A = A; q.B = B; q.C = C; q.D = D; q.vf = vfp; q.noise = noisep;
        q.M = Mm; q.N = Nn; q.K = Kk; q.lda = lda; q.ldb = ldb; q.ldc = ldc;
        q.sA = sA; q.sB = sB; q.sC = sC; q.sD = sD;
        q.alpha = alpha; q.dcoef = dcoef; q.addI = addI;
        q.sVf = sVf; q.sNoise = sNoise;
        dim3 g(Nn / 64, Mm / 64, batch);
        if (EFf)                gemm_k<1,0,0,1><<<g, b256, 0, stream>>>(q);
        else if (ACCf)          gemm_k<0,1,1,0><<<g, b256, 0, stream>>>(q);
        else if (TAf && TBf)    gemm_k<1,1,0,0><<<g, b256, 0, stream>>>(q);
        else if (TAf)           gemm_k<1,0,0,0><<<g, b256, 0, stream>>>(q);
        else if (TBf)           gemm_k<0,1,0,0><<<g, b256, 0, stream>>>(q);
        else                    gemm_k<0,0,0,0><<<g, b256, 0, stream>>>(q);
    };

    // scalars
    max1_kernel<<<256, b256, 0, stream>>>(Kuu, S_ * MM_, part);
    max2_kernel<<<1, b256, 0, stream>>>(part, ws);
    prep_kernel<<<1, b256, 0, stream>>>(Lloc, Lscale, ws);
    scaleL_kernel<<<256, b256, 0, stream>>>(Lloc, ws, Lbuf);
    copyjit_kernel<<<4096, b256, 0, stream>>>(Kuu, ws, cholK);

    // KuuL = Kuu @ L
    run(Kuu, Lbuf, KuuL, 256,256,256, 256,256,256, MM_,0,MM_, 0,0,0, 1.f,
        nullptr,0,0.f,0, nullptr,0,nullptr,0,0, S_);
    // lKlpI = L^T @ KuuL + I   (into choll buffer)
    run(Lbuf, KuuL, choll, 256,256,256, 256,256,256, 0,MM_,MM_, 1,0,0, 1.f,
        nullptr,0,0.f,1, nullptr,0,nullptr,0,0, S_);

    chol_kernel<<<32, b256, 0, stream>>>(cholK, choll);
    trinv_kernel<<<dim3(4, 32), b256, 0, stream>>>(cholK, choll, TK, Tl);

    // KuuInv = TK^T @ TK ; lKlpIinv = Tl^T @ Tl
    run(TK, TK, KuuInv, 256,256,256, 256,256,256, MM_,MM_,MM_, 1,0,0, 1.f,
        nullptr,0,0.f,0, nullptr,0,nullptr,0,0, S_);
    run(Tl, Tl, lKlpIi, 256,256,256, 256,256,256, MM_,MM_,MM_, 1,0,0, 1.f,
        nullptr,0,0.f,0, nullptr,0,nullptr,0,0, S_);
    // Stmp = KuuL @ lKlpIinv
    run(KuuL, lKlpIi, Stmp, 256,256,256, 256,256,256, MM_,MM_,MM_, 0,0,0, 1.f,
        nullptr,0,0.f,0, nullptr,0,nullptr,0,0, S_);
    // Sigma = Kuu - Stmp @ KuuL^T
    run(Stmp, KuuL, Sigma, 256,256,256, 256,256,256, MM_,MM_,MM_, 0,1,0, -1.f,
        Kuu,MM_,1.f,0, nullptr,0,nullptr,0,0, S_);

    // UP = L @ (L^T @ u_param^T)   (batch 1)
    run(Lbuf, u_param, UPt, 256,256,256, 256,256,256, 0,0,0, 1,1,0, 1.f,
        nullptr,0,0.f,0, nullptr,0,nullptr,0,0, 1);
    run(Lbuf, UPt, UP, 256,256,256, 256,256,256, 0,0,0, 0,0,0, 1.f,
        nullptr,0,0.f,0, nullptr,0,nullptr,0,0, 1);

    // RHS = TK^T @ noise_inv^T + UP
    run(TK, noise_inv, RHS, 256,256,256, 256,256,256, MM_,MM_,MM_, 1,1,0, 1.f,
        UP,0,1.f,0, nullptr,0,nullptr,0,0, S_);
    // RHS += L @ noise_L^T
    run(Lbuf, noise_L, RHS, 256,256,256, 256,256,256, 0,MM_,MM_, 0,1,1, 1.f,
        nullptr,0,0.f,0, nullptr,0,nullptr,0,0, S_);
    // U = Sigma @ RHS
    run(Sigma, RHS, U, 256,256,256, 256,256,256, MM_,MM_,MM_, 0,0,0, 1.f,
        nullptr,0,0.f,0, nullptr,0,nullptr,0,0, S_);

    ucopy_kernel<<<4096, b256, 0, stream>>>(U, out);

    for (int f0 = 0; f0 < NF_; f0 += nfc) {
        int w = NF_ - f0; if (w > nfc) w = nfc;
        // A = KuuInv @ Kuf[:, f0:f0+w]
        run(KuuInv, Kuf + f0, Achunk, 256, w, 256, 256, NF_, w,
            MM_, (long)M_ * NF_, (long)M_ * w, 0,0,0, 1.f,
            nullptr,0,0.f,0, nullptr,0,nullptr,0,0, S_);
        // sqrt(Vf)
        vf_kernel<<<dim3((w + 255) / 256, S_), b256, 0, stream>>>(Achunk, Kuf, Kff, Vf, f0, w);
        // out_f = A^T @ U + sqrt(Vf)*noise_f
        run(Achunk, U, out + (long)(M_ + f0) * OUT_, w, 256, 256, w, 256, 256,
            (long)M_ * w, MM_, (long)ROWS_ * OUT_, 1,0,0, 1.f,
            nullptr,0,0.f,0, Vf + f0, NF_, noise_f + (long)f0 * OUT_, (long)NF_ * OUT_, 1, S_);
    }
}

// Round 2
// 1723.358 us; speedup vs baseline: 1.9862x; 1.9862x over previous
//
#include <hip/hip_runtime.h>
#include <math.h>

#define S_ 16
#define M_ 256
#define NF_ 4096
#define OUT_ 256
#define ROWS_ (M_ + NF_)     // 4352
#define JITTER_ 1e-8f
#define MM_ (M_ * M_)        // 65536

// ---------------- small prep kernels ----------------

__global__ void max1_kernel(const float* __restrict__ x, int n, float* part) {
    __shared__ float red[256];
    int tid = threadIdx.x;
    float m = -3.4e38f;
    for (int i = blockIdx.x * blockDim.x + tid; i < n; i += gridDim.x * blockDim.x)
        m = fmaxf(m, x[i]);
    red[tid] = m; __syncthreads();
    for (int s = 128; s > 0; s >>= 1) {
        if (tid < s) red[tid] = fmaxf(red[tid], red[tid + s]);
        __syncthreads();
    }
    if (tid == 0) part[blockIdx.x] = red[0];
}

__global__ void max2_kernel(const float* part, float* ws) {
    __shared__ float red[256];
    int tid = threadIdx.x;
    red[tid] = part[tid]; __syncthreads();
    for (int s = 128; s > 0; s >>= 1) {
        if (tid < s) red[tid] = fmaxf(red[tid], red[tid + s]);
        __syncthreads();
    }
    if (tid == 0) { ws[0] = red[0]; ws[2] = JITTER_ * red[0]; }
}

__global__ void prep_kernel(const float* __restrict__ Lloc, const float* __restrict__ Lscale, float* ws) {
    __shared__ float red[256];
    int tid = threadIdx.x;
    red[tid] = Lloc[tid * M_ + tid];
    __syncthreads();
    for (int s = 128; s > 0; s >>= 1) {
        if (tid < s) red[tid] += red[tid + s];
        __syncthreads();
    }
    if (tid == 0) {
        float norm = red[0] / (float)M_;
        ws[1] = expf(Lscale[0]) / norm;
    }
}

__global__ void scaleL_kernel(const float* __restrict__ Lloc, const float* __restrict__ ws, float* __restrict__ L) {
    int i = blockIdx.x * blockDim.x + threadIdx.x;
    if (i < MM_) L[i] = Lloc[i] * ws[1];
}

__global__ void copyjit_kernel(const float* __restrict__ Kuu, const float* __restrict__ ws, float* __restrict__ dst) {
    int i = blockIdx.x * blockDim.x + threadIdx.x;
    if (i < S_ * MM_) {
        float v = Kuu[i];
        int r = (i >> 8) & 255;
        int c = i & 255;
        if (r == c) v += ws[2];
        dst[i] = v;
    }
}

// ---------------- batched Cholesky, row-per-thread rank-1 ----------------
// Row-padded packed lower triangle: row i = 4m+t has base 4(m+1)(2m+t), padded
// to 16B so float4 LDS ops are aligned. Thread i owns row i. Column k staged
// into a contiguous buffer (broadcast reads); next column's staging value is
// extracted from the updated first chunk -> 1 sync per column.
// Input: full symmetric matrix; output: lower triangle overwritten with chol
// factor (upper left untouched). LDL-style updates, scaled on writeback.

__global__ __launch_bounds__(256) void chol_kernel(float* bufA, float* bufB) {
    int blk = blockIdx.x;                       // 0..31
    float* Ag = (blk < S_) ? (bufA + (long)blk * MM_) : (bufB + (long)(blk - S_) * MM_);
    __shared__ float P[33280];                  // 133120 B padded packed triangle
    __shared__ float colbuf[2][256];
    __shared__ float dsr[256];
    int tid = threadIdx.x;
    int mg = tid >> 2, tg = tid & 3;
    int base = 4 * (mg + 1) * (2 * mg + tg);    // row tid's base (float index)

    // cooperative load of lower triangle (coalesced per row)
    for (int i = 0; i < M_; i++) {
        int mi = i >> 2, ti = i & 3;
        int bi = 4 * (mi + 1) * (2 * mi + ti);
        for (int j = tid; j <= i; j += 256) P[bi + j] = Ag[(long)i * M_ + j];
    }
    __syncthreads();
    colbuf[0][tid] = P[base];                   // column 0
    int cb = 0;
    for (int k = 0; k < M_ - 1; k++) {
        __syncthreads();                        // column k staged & prev updates done
        float* ccur = colbuf[cb];
        float* cnxt = colbuf[cb ^ 1];
        if (tid > k) {
            float rd = 1.0f / ccur[k];
            float s = ccur[tid] * rd;
            int c0 = (k + 1) >> 2;
            int c1 = tid >> 2;
            float4* prow = (float4*)&P[base];
            const float4* pcol = (const float4*)ccur;
            // first (possibly partial) chunk, predicated on j > k
            float4 rv = prow[c0];
            float4 cv = pcol[c0];
            int jb = c0 << 2;
            if (jb + 0 > k) rv.x -= s * cv.x;
            if (jb + 1 > k) rv.y -= s * cv.y;
            if (jb + 2 > k) rv.z -= s * cv.z;
            if (jb + 3 > k) rv.w -= s * cv.w;
            prow[c0] = rv;
            // stage next column's value for this row from registers
            int e = (k + 1) & 3;
            cnxt[tid] = (e == 0) ? rv.x : (e == 1) ? rv.y : (e == 2) ? rv.z : rv.w;
            // full chunks (pad elements beyond row end are write-garbage, never read)
            #pragma unroll 2
            for (int c = c0 + 1; c <= c1; c++) {
                float4 r2 = prow[c];
                float4 c2 = pcol[c];
                r2.x -= s * c2.x; r2.y -= s * c2.y;
                r2.z -= s * c2.z; r2.w -= s * c2.w;
                prow[c] = r2;
            }
        }
        cb ^= 1;
    }
    __syncthreads();
    dsr[tid] = rsqrtf(P[base + tid]);           // own diag is final
    __syncthreads();
    // writeback lower triangle scaled to true Cholesky factor (coalesced per row)
    for (int i = 0; i < M_; i++) {
        int mi = i >> 2, ti = i & 3;
        int bi = 4 * (mi + 1) * (2 * mi + ti);
        for (int j = tid; j <= i; j += 256) Ag[(long)i * M_ + j] = P[bi + j] * dsr[j];
    }
}

// ---------------- batched lower-triangular inverse ----------------
// Columns are independent solves L x = e_j. Block handles 64 columns (j = 4c+cb),
// 4 threads per column each owning a 64-row quarter of the accumulator (in LDS).

__global__ __launch_bounds__(256) void trinv_kernel(const float* bufA, const float* bufB,
                                                    float* TA_, float* TB_) {
    int mat = blockIdx.y;      // 0..31
    int cb  = blockIdx.x;      // 0..3
    const float* Lg = (mat < S_) ? (bufA + (long)mat * MM_) : (bufB + (long)(mat - S_) * MM_);
    float* Tg       = (mat < S_) ? (TA_ + (long)mat * MM_) : (TB_ + (long)(mat - S_) * MM_);
    __shared__ float X[M_ * 65];    // [k][c], stride 65 to spread banks
    __shared__ float diag[M_];
    int tid = threadIdx.x;
    int c = tid >> 2;          // 0..63
    int q = tid & 3;           // 0..3
    int j = (c << 2) | cb;     // this thread-group's column
    for (int i = tid; i < M_ * 65; i += 256) X[i] = 0.f;
    for (int i = tid; i < M_; i += 256) diag[i] = Lg[i * M_ + i];
    __syncthreads();
    for (int t = 0; t < M_; t++) {
        if (q == (t >> 6)) {
            float x = 0.f;
            if (j <= t) {
                float acc = X[t * 65 + c];
                x = (((t == j) ? 1.0f : 0.0f) - acc) / diag[t];
                X[t * 65 + c] = x;
            }
            Tg[t * M_ + j] = x;   // also zeroes the upper triangle
        }
        __syncthreads();
        if (j <= t) {
            float x = X[t * 65 + c];
            int kend = (q << 6) + 64;
            int kbeg = (q << 6);
            if (kbeg < t + 1) kbeg = t + 1;
            for (int k = kbeg; k < kend; k++) {
                X[k * 65 + c] += Lg[k * M_ + t] * x;
            }
        }
        // no second sync needed: slot (t+1) is owned by the same thread that reads it next
    }
}

// ---------------- generic tiled fp32 GEMM ----------------
// C = alpha*opA(A)@opB(B) [+ C if ACC] [+ dcoef*D] [+ I if addI]
// [+ vf[row]*noise[row*256+col] if EF]    (vf holds sqrt(Vf))

struct GemmParams {
    const float* A; const float* B; float* C;
    const float* D;
    const float* vf; const float* noise;
    int M, N, K;
    int lda, ldb, ldc;
    long sA, sB, sC, sD;
    float alpha, dcoef;
    int addI;
    long sVf, sNoise;
};

template<int TAf, int TBf, int ACCf, int EFf>
__global__ __launch_bounds__(256) void gemm_k(GemmParams p) {
    int bz = blockIdx.z;
    const float* A = p.A + (long)bz * p.sA;
    const float* B = p.B + (long)bz * p.sB;
    float* C = p.C + (long)bz * p.sC;
    int bm = blockIdx.y * 64, bn = blockIdx.x * 64;
    __shared__ float As[16][68];
    __shared__ float Bs[16][68];
    int tid = threadIdx.x;
    int tx = tid & 15, ty = tid >> 4;
    float acc[4][4] = {};
    for (int k0 = 0; k0 < p.K; k0 += 16) {
        if (TAf) {            // opA(i,k) = A[k*lda+i]  -> contiguous in i
            int i = tid & 63, kk0 = tid >> 6;
            #pragma unroll
            for (int r = 0; r < 4; r++) {
                int kk = kk0 + r * 4;
                As[kk][i] = A[(long)(k0 + kk) * p.lda + bm + i];
            }
        } else {              // opA(i,k) = A[i*lda+k]  -> contiguous in k
            int kk = tid & 15, i0 = tid >> 4;
            #pragma unroll
            for (int r = 0; r < 4; r++) {
                int i = i0 + r * 16;
                As[kk][i] = A[(long)(bm + i) * p.lda + k0 + kk];
            }
        }
        if (TBf) {            // opB(k,j) = B[j*ldb+k]  -> contiguous in k
            int kk = tid & 15, j0 = tid >> 4;
            #pragma unroll
            for (int r = 0; r < 4; r++) {
                int jj = j0 + r * 16;
                Bs[kk][jj] = B[(long)(bn + jj) * p.ldb + k0 + kk];
            }
        } else {              // opB(k,j) = B[k*ldb+j]  -> contiguous in j
            int jj = tid & 63, kk0 = tid >> 6;
            #pragma unroll
            for (int r = 0; r < 4; r++) {
                int kk = kk0 + r * 4;
                Bs[kk][jj] = B[(long)(k0 + kk) * p.ldb + bn + jj];
            }
        }
        __syncthreads();
        #pragma unroll
        for (int kk = 0; kk < 16; kk++) {
            float a[4], b4[4];
            #pragma unroll
            for (int u = 0; u < 4; u++) a[u] = As[kk][(ty << 2) + u];
            #pragma unroll
            for (int v = 0; v < 4; v++) b4[v] = Bs[kk][(tx << 2) + v];
            #pragma unroll
            for (int u = 0; u < 4; u++)
                #pragma unroll
                for (int v = 0; v < 4; v++)
                    acc[u][v] = fmaf(a[u], b4[v], acc[u][v]);
        }
        __syncthreads();
    }
    #pragma unroll
    for (int u = 0; u < 4; u++) {
        int row = bm + (ty << 2) + u;
        float4 outv;
        float* o = (float*)&outv;
        #pragma unroll
        for (int v = 0; v < 4; v++) {
            int col = bn + (tx << 2) + v;
            float val = p.alpha * acc[u][v];
            if (ACCf) val += C[(long)row * p.ldc + col];
            if (p.D)  val += p.dcoef * p.D[(long)bz * p.sD + (long)row * p.ldc + col];
            if (p.addI && row == col) val += 1.0f;
            if (EFf)  val += p.vf[(long)bz * p.sVf + row] *
                             p.noise[(long)bz * p.sNoise + (long)row * 256 + col];
            o[v] = val;
        }
        *(float4*)&C[(long)row * p.ldc + bn + (tx << 2)] = outv;
    }
}

// ---------------- Vf = sqrt(Kff_diag - sum_m A*Kuf) ----------------

__global__ void vf_kernel(const float* __restrict__ Achunk, const float* __restrict__ Kuf,
                          const float* __restrict__ Kff, float* __restrict__ Vf,
                          int f0, int nfc) {
    int s = blockIdx.y;
    int fl = blockIdx.x * 256 + threadIdx.x;
    if (fl >= nfc) return;
    const float* Ab = Achunk + (long)s * M_ * nfc;
    const float* Kb = Kuf + (long)s * M_ * NF_ + f0;
    float acc = 0.f;
    for (int m = 0; m < M_; m++)
        acc += Ab[(long)m * nfc + fl] * Kb[(long)m * NF_ + fl];
    float v = Kff[(long)s * NF_ + f0 + fl] - acc;
    Vf[(long)s * NF_ + f0 + fl] = sqrtf(v);
}

__global__ void ucopy_kernel(const float* __restrict__ U, float* __restrict__ out) {
    int i = blockIdx.x * blockDim.x + threadIdx.x;
    if (i < S_ * M_ * OUT_) {
        int s = i >> 16;
        int rc = i & 65535;
        out[(long)s * ROWS_ * OUT_ + rc] = U[i];
    }
}

// ---------------- host ----------------

extern "C" void kernel_launch(void* const* d_in, const int* in_sizes, int n_in,
                              void* d_out, int out_size, void* d_ws, size_t ws_size,
                              hipStream_t stream) {
    const float* Kuu       = (const float*)d_in[0];
    const float* Kuf       = (const float*)d_in[1];
    const float* Kff       = (const float*)d_in[2];
    const float* Lloc      = (const float*)d_in[3];
    const float* Lscale    = (const float*)d_in[4];
    const float* u_param   = (const float*)d_in[5];
    const float* noise_inv = (const float*)d_in[6];
    const float* noise_L   = (const float*)d_in[7];
    const float* noise_f   = (const float*)d_in[8];
    float* out = (float*)d_out;
    float* ws  = (float*)d_ws;

    long off = 1024;
    float* part   = ws + 16;
    float* Lbuf   = ws + off; off += MM_;
    float* UPt    = ws + off; off += MM_;
    float* UP     = ws + off; off += MM_;
    float* Vf     = ws + off; off += (long)S_ * NF_;
    float* cholK  = ws + off; off += (long)S_ * MM_;
    float* TK     = ws + off; off += (long)S_ * MM_;
    float* KuuL   = ws + off; off += (long)S_ * MM_;
    float* choll  = ws + off; off += (long)S_ * MM_;
    float* Tl     = ws + off; off += (long)S_ * MM_;
    float* KuuInv = ws + off; off += (long)S_ * MM_;
    float* lKlpIi = ws + off; off += (long)S_ * MM_;
    float* Stmp   = ws + off; off += (long)S_ * MM_;
    float* Sigma  = ws + off; off += (long)S_ * MM_;
    float* RHS    = ws + off; off += (long)S_ * MM_;
    float* U      = ws + off; off += (long)S_ * MM_;
    float* Achunk = ws + off;
    long avail = (long)(ws_size / 4) - off;
    int nfc = (int)(avail / ((long)S_ * M_));
    nfc = (nfc / 64) * 64;
    if (nfc > NF_) nfc = NF_;
    if (nfc < 64) nfc = 64;

    dim3 b256(256);

    auto run = [&](const float* A, const float* B, float* C,
                   int Mm, int Nn, int Kk, int lda, int ldb, int ldc,
                   long sA, long sB, long sC,
                   int TAf, int TBf, int ACCf, float alpha,
                   const float* D, long sD, float dcoef, int addI,
                   const float* vfp, long sVf, const float* noisep, long sNoise, int EFf,
                   int batch) {
        GemmParams q;
        q.A = A; q.B = B; q.C = C; q.D = D; q.vf = vfp; q.noise = noisep;
        q.M = Mm; q.N = Nn; q.K = Kk; q.lda = lda; q.ldb = ldb; q.ldc = ldc;
        q.sA = sA; q.sB = sB; q.sC = sC; q.sD = sD;
        q.alpha = alpha; q.dcoef = dcoef; q.addI = addI;
        q.sVf = sVf; q.sNoise = sNoise;
        dim3 g(Nn / 64, Mm / 64, batch);
        if (EFf)                gemm_k<1,0,0,1><<<g, b256, 0, stream>>>(q);
        else if (ACCf)          gemm_k<0,1,1,0><<<g, b256, 0, stream>>>(q);
        else if (TAf && TBf)    gemm_k<1,1,0,0><<<g, b256, 0, stream>>>(q);
        else if (TAf)           gemm_k<1,0,0,0><<<g, b256, 0, stream>>>(q);
        else if (TBf)           gemm_k<0,1,0,0><<<g, b256, 0, stream>>>(q);
        else                    gemm_k<0,0,0,0><<<g, b256, 0, stream>>>(q);
    };

    // scalars
    max1_kernel<<<256, b256, 0, stream>>>(Kuu, S_ * MM_, part);
    max2_kernel<<<1, b256, 0, stream>>>(part, ws);
    prep_kernel<<<1, b256, 0, stream>>>(Lloc, Lscale, ws);
    scaleL_kernel<<<256, b256, 0, stream>>>(Lloc, ws, Lbuf);
    copyjit_kernel<<<4096, b256, 0, stream>>>(Kuu, ws, cholK);

    // KuuL = Kuu @ L
    run(Kuu, Lbuf, KuuL, 256,256,256, 256,256,256, MM_,0,MM_, 0,0,0, 1.f,
        nullptr,0,0.f,0, nullptr,0,nullptr,0,0, S_);
    // lKlpI = L^T @ KuuL + I   (into choll buffer)
    run(Lbuf, KuuL, choll, 256,256,256, 256,256,256, 0,MM_,MM_, 1,0,0, 1.f,
        nullptr,0,0.f,1, nullptr,0,nullptr,0,0, S_);

    chol_kernel<<<32, b256, 0, stream>>>(cholK, choll);
    trinv_kernel<<<dim3(4, 32), b256, 0, stream>>>(cholK, choll, TK, Tl);

    // KuuInv = TK^T @ TK ; lKlpIinv = Tl^T @ Tl
    run(TK, TK, KuuInv, 256,256,256, 256,256,256, MM_,MM_,MM_, 1,0,0, 1.f,
        nullptr,0,0.f,0, nullptr,0,nullptr,0,0, S_);
    run(Tl, Tl, lKlpIi, 256,256,256, 256,256,256, MM_,MM_,MM_, 1,0,0, 1.f,
        nullptr,0,0.f,0, nullptr,0,nullptr,0,0, S_);
    // Stmp = KuuL @ lKlpIinv
    run(KuuL, lKlpIi, Stmp, 256,256,256, 256,256,256, MM_,MM_,MM_, 0,0,0, 1.f,
        nullptr,0,0.f,0, nullptr,0,nullptr,0,0, S_);
    // Sigma = Kuu - Stmp @ KuuL^T
    run(Stmp, KuuL, Sigma, 256,256,256, 256,256,256, MM_,MM_,MM_, 0,1,0, -1.f,
        Kuu,MM_,1.f,0, nullptr,0,nullptr,0,0, S_);

    // UP = L @ (L^T @ u_param^T)   (batch 1)
    run(Lbuf, u_param, UPt, 256,256,256, 256,256,256, 0,0,0, 1,1,0, 1.f,
        nullptr,0,0.f,0, nullptr,0,nullptr,0,0, 1);
    run(Lbuf, UPt, UP, 256,256,256, 256,256,256, 0,0,0, 0,0,0, 1.f,
        nullptr,0,0.f,0, nullptr,0,nullptr,0,0, 1);

    // RHS = TK^T @ noise_inv^T + UP
    run(TK, noise_inv, RHS, 256,256,256, 256,256,256, MM_,MM_,MM_, 1,1,0, 1.f,
        UP,0,1.f,0, nullptr,0,nullptr,0,0, S_);
    // RHS += L @ noise_L^T
    run(Lbuf, noise_L, RHS, 256,256,256, 256,256,256, 0,MM_,MM_, 0,1,1, 1.f,
        nullptr,0,0.f,0, nullptr,0,nullptr,0,0, S_);
    // U = Sigma @ RHS
    run(Sigma, RHS, U, 256,256,256, 256,256,256, MM_,MM_,MM_, 0,0,0, 1.f,
        nullptr,0,0.f,0, nullptr,0,nullptr,0,0, S_);

    ucopy_kernel<<<4096, b256, 0, stream>>>(U, out);

    for (int f0 = 0; f0 < NF_; f0 += nfc) {
        int w = NF_ - f0; if (w > nfc) w = nfc;
        // A = KuuInv @ Kuf[:, f0:f0+w]
        run(KuuInv, Kuf + f0, Achunk, 256, w, 256, 256, NF_, w,
            MM_, (long)M_ * NF_, (long)M_ * w, 0,0,0, 1.f,
            nullptr,0,0.f,0, nullptr,0,nullptr,0,0, S_);
        // sqrt(Vf)
        vf_kernel<<<dim3((w + 255) / 256, S_), b256, 0, stream>>>(Achunk, Kuf, Kff, Vf, f0, w);
        // out_f = A^T @ U + sqrt(Vf)*noise_f
        run(Achunk, U, out + (long)(M_ + f0) * OUT_, w, 256, 256, w, 256, 256,
            (long)M_ * w, MM_, (long)ROWS_ * OUT_, 1,0,0, 1.f,
            nullptr,0,0.f,0, Vf + f0, NF_, noise_f + (long)f0 * OUT_, (long)NF_ * OUT_, 1, S_);
    }
}

// Round 3
// 1307.282 us; speedup vs baseline: 2.6183x; 1.3183x over previous
//
#include <hip/hip_runtime.h>
#include <math.h>

#define S_ 16
#define M_ 256
#define NF_ 4096
#define OUT_ 256
#define ROWS_ (M_ + NF_)     // 4352
#define JITTER_ 1e-8f
#define MM_ (M_ * M_)        // 65536

// ---------------- small prep kernels ----------------

__global__ void max1_kernel(const float* __restrict__ x, int n, float* part) {
    __shared__ float red[256];
    int tid = threadIdx.x;
    float m = -3.4e38f;
    for (int i = blockIdx.x * blockDim.x + tid; i < n; i += gridDim.x * blockDim.x)
        m = fmaxf(m, x[i]);
    red[tid] = m; __syncthreads();
    for (int s = 128; s > 0; s >>= 1) {
        if (tid < s) red[tid] = fmaxf(red[tid], red[tid + s]);
        __syncthreads();
    }
    if (tid == 0) part[blockIdx.x] = red[0];
}

__global__ void max2_kernel(const float* part, float* ws) {
    __shared__ float red[256];
    int tid = threadIdx.x;
    red[tid] = part[tid]; __syncthreads();
    for (int s = 128; s > 0; s >>= 1) {
        if (tid < s) red[tid] = fmaxf(red[tid], red[tid + s]);
        __syncthreads();
    }
    if (tid == 0) { ws[0] = red[0]; ws[2] = JITTER_ * red[0]; }
}

__global__ void prep_kernel(const float* __restrict__ Lloc, const float* __restrict__ Lscale, float* ws) {
    __shared__ float red[256];
    int tid = threadIdx.x;
    red[tid] = Lloc[tid * M_ + tid];
    __syncthreads();
    for (int s = 128; s > 0; s >>= 1) {
        if (tid < s) red[tid] += red[tid + s];
        __syncthreads();
    }
    if (tid == 0) {
        float norm = red[0] / (float)M_;
        ws[1] = expf(Lscale[0]) / norm;
    }
}

__global__ void scaleL_kernel(const float* __restrict__ Lloc, const float* __restrict__ ws, float* __restrict__ L) {
    int i = blockIdx.x * blockDim.x + threadIdx.x;
    if (i < MM_) L[i] = Lloc[i] * ws[1];
}

__global__ void copyjit_kernel(const float* __restrict__ Kuu, const float* __restrict__ ws, float* __restrict__ dst) {
    int i = blockIdx.x * blockDim.x + threadIdx.x;
    if (i < S_ * MM_) {
        float v = Kuu[i];
        int r = (i >> 8) & 255;
        int c = i & 255;
        if (r == c) v += ws[2];
        dst[i] = v;
    }
}

// ---------------- batched blocked Cholesky (BK=16) ----------------
// Padded packed lower triangle in LDS (row 4m+t: float4 base (m+1)(2m+t),
// m+1 chunks). Thread t owns row t; its 16-wide panel chunk lives in regs.
// Per panel: (A) diag 16x16 factored by one wave via shuffles, published to
// piv[][]; (B) trailing rows forward-solve in regs vs piv (uniform broadcast
// reads); (C) panel written to panT (transposed) + back to P; (D) rank-16
// trailing update, float4 rows vs wave-uniform float4 panT reads. 3 syncs
// per panel. Output: true Cholesky factor in lower triangle of Ag (a few
// pad elements above the diagonal get garbage; only lower tri is consumed).

__global__ __launch_bounds__(256) void chol_kernel(float* bufA, float* bufB) {
    int blk = blockIdx.x;                       // 0..31
    float* Ag = (blk < S_) ? (bufA + (long)blk * MM_) : (bufB + (long)(blk - S_) * MM_);
    __shared__ float P[33280];                  // 133120 B
    __shared__ float panT[16][256];             // 16 KB, [panel col][global row]
    __shared__ float piv[16][18];               // [j][i<j]=L[k0+j][i]; [j][16]=1/d_j
    float4* P4 = (float4*)P;
    int tid = threadIdx.x;
    int lane = tid & 63, wid = tid >> 6;
    int mg = tid >> 2, tg = tid & 3;
    int b4 = (mg + 1) * (2 * mg + tg);          // float4 base of row tid

    // ---- load lower triangle, wave-cooperative, coalesced ----
    for (int i = wid; i < M_; i += 4) {
        int m = i >> 2, t4 = i & 3;
        int rb4 = (m + 1) * (2 * m + t4);
        if (lane <= m) P4[rb4 + lane] = ((const float4*)Ag)[i * 64 + lane];
    }
    __syncthreads();

    float preg[16];
    for (int p = 0; p < 16; p++) {
        int k0 = p << 4;
        int c0 = k0 >> 2;
        // ---- panel chunk -> registers ----
        #pragma unroll
        for (int r = 0; r < 4; r++) {
            float4 v = make_float4(0.f, 0.f, 0.f, 0.f);
            if (tid >= k0 && c0 + r <= mg) v = P4[b4 + c0 + r];
            preg[4 * r + 0] = v.x; preg[4 * r + 1] = v.y;
            preg[4 * r + 2] = v.z; preg[4 * r + 3] = v.w;
        }
        // ---- (A) diag block: one wave, registers + shuffles ----
        int dw = k0 >> 6;
        int lb = k0 & 63;
        if (wid == dw) {
            int dj = lane - lb;
            bool isdiag = (dj >= 0 && dj < 16);
            float myinv = 0.f;
            #pragma unroll
            for (int j = 0; j < 16; j++) {
                float app = __shfl(preg[j], lb + j, 64);
                float d = sqrtf(app);
                float inv = 1.0f / d;
                if (isdiag) {
                    if (dj == j) { preg[j] = d; myinv = inv; }
                    else if (dj > j) preg[j] *= inv;
                }
                #pragma unroll
                for (int j2 = j + 1; j2 < 16; j2++) {
                    float Lj2 = __shfl(preg[j], lb + j2, 64);
                    if (isdiag && dj >= j2) preg[j2] -= preg[j] * Lj2;
                }
            }
            if (isdiag) {
                #pragma unroll
                for (int i = 0; i < 16; i++) piv[dj][i] = preg[i];
                piv[dj][16] = myinv;
            }
        }
        __syncthreads();
        // ---- (B) trailing rows: forward substitution in registers ----
        if (tid > k0 + 15) {
            float x[16];
            #pragma unroll
            for (int j = 0; j < 16; j++) {
                float acc = preg[j];
                #pragma unroll
                for (int i = 0; i < 16; i++)
                    if (i < j) acc -= x[i] * piv[j][i];
                x[j] = acc * piv[j][16];
            }
            #pragma unroll
            for (int j = 0; j < 16; j++) preg[j] = x[j];
        }
        // ---- (C) publish panel (transposed) + write L back to P ----
        if (tid >= k0) {
            #pragma unroll
            for (int j = 0; j < 16; j++) panT[j][tid] = preg[j];
            #pragma unroll
            for (int r = 0; r < 4; r++) {
                int c = c0 + r;
                if (c <= mg)
                    P4[b4 + c] = make_float4(preg[4 * r], preg[4 * r + 1],
                                             preg[4 * r + 2], preg[4 * r + 3]);
            }
        }
        __syncthreads();
        // ---- (D) rank-16 trailing update ----
        int clo = c0 + 4;
        int chi = (wid << 4) + 15;              // max chunk this wave's rows need
        for (int c = clo; c <= chi; c++) {
            if (tid > k0 + 15 && c <= mg) {
                float4 rv = P4[b4 + c];
                #pragma unroll
                for (int tt = 0; tt < 16; tt++) {
                    float4 pv = *(const float4*)&panT[tt][c << 2];
                    rv.x -= preg[tt] * pv.x;
                    rv.y -= preg[tt] * pv.y;
                    rv.z -= preg[tt] * pv.z;
                    rv.w -= preg[tt] * pv.w;
                }
                P4[b4 + c] = rv;
            }
        }
        __syncthreads();
    }

    // ---- writeback, wave-cooperative, coalesced ----
    for (int i = wid; i < M_; i += 4) {
        int m = i >> 2, t4 = i & 3;
        int rb4 = (m + 1) * (2 * m + t4);
        if (lane <= m) ((float4*)Ag)[i * 64 + lane] = P4[rb4 + lane];
    }
}

// ---------------- batched lower-triangular inverse ----------------
// Columns are independent solves L x = e_j. Block handles 64 columns (j = 4c+cb),
// 4 threads per column each owning a 64-row quarter of the accumulator (in LDS).

__global__ __launch_bounds__(256) void trinv_kernel(const float* bufA, const float* bufB,
                                                    float* TA_, float* TB_) {
    int mat = blockIdx.y;      // 0..31
    int cb  = blockIdx.x;      // 0..3
    const float* Lg = (mat < S_) ? (bufA + (long)mat * MM_) : (bufB + (long)(mat - S_) * MM_);
    float* Tg       = (mat < S_) ? (TA_ + (long)mat * MM_) : (TB_ + (long)(mat - S_) * MM_);
    __shared__ float X[M_ * 65];    // [k][c], stride 65 to spread banks
    __shared__ float diag[M_];
    int tid = threadIdx.x;
    int c = tid >> 2;          // 0..63
    int q = tid & 3;           // 0..3
    int j = (c << 2) | cb;     // this thread-group's column
    for (int i = tid; i < M_ * 65; i += 256) X[i] = 0.f;
    for (int i = tid; i < M_; i += 256) diag[i] = Lg[i * M_ + i];
    __syncthreads();
    for (int t = 0; t < M_; t++) {
        if (q == (t >> 6)) {
            float x = 0.f;
            if (j <= t) {
                float acc = X[t * 65 + c];
                x = (((t == j) ? 1.0f : 0.0f) - acc) / diag[t];
                X[t * 65 + c] = x;
            }
            Tg[t * M_ + j] = x;   // also zeroes the upper triangle
        }
        __syncthreads();
        if (j <= t) {
            float x = X[t * 65 + c];
            int kend = (q << 6) + 64;
            int kbeg = (q << 6);
            if (kbeg < t + 1) kbeg = t + 1;
            for (int k = kbeg; k < kend; k++) {
                X[k * 65 + c] += Lg[k * M_ + t] * x;
            }
        }
        // no second sync needed: slot (t+1) is owned by the same thread that reads it next
    }
}

// ---------------- generic tiled fp32 GEMM ----------------
// C = alpha*opA(A)@opB(B) [+ C if ACC] [+ dcoef*D] [+ I if addI]
// [+ vf[row]*noise[row*256+col] if EF]    (vf holds sqrt(Vf))

struct GemmParams {
    const float* A; const float* B; float* C;
    const float* D;
    const float* vf; const float* noise;
    int M, N, K;
    int lda, ldb, ldc;
    long sA, sB, sC, sD;
    float alpha, dcoef;
    int addI;
    long sVf, sNoise;
};

template<int TAf, int TBf, int ACCf, int EFf>
__global__ __launch_bounds__(256) void gemm_k(GemmParams p) {
    int bz = blockIdx.z;
    const float* A = p.A + (long)bz * p.sA;
    const float* B = p.B + (long)bz * p.sB;
    float* C = p.C + (long)bz * p.sC;
    int bm = blockIdx.y * 64, bn = blockIdx.x * 64;
    __shared__ float As[16][68];
    __shared__ float Bs[16][68];
    int tid = threadIdx.x;
    int tx = tid & 15, ty = tid >> 4;
    float acc[4][4] = {};
    for (int k0 = 0; k0 < p.K; k0 += 16) {
        if (TAf) {            // opA(i,k) = A[k*lda+i]  -> contiguous in i
            int i = tid & 63, kk0 = tid >> 6;
            #pragma unroll
            for (int r = 0; r < 4; r++) {
                int kk = kk0 + r * 4;
                As[kk][i] = A[(long)(k0 + kk) * p.lda + bm + i];
            }
        } else {              // opA(i,k) = A[i*lda+k]  -> contiguous in k
            int kk = tid & 15, i0 = tid >> 4;
            #pragma unroll
            for (int r = 0; r < 4; r++) {
                int i = i0 + r * 16;
                As[kk][i] = A[(long)(bm + i) * p.lda + k0 + kk];
            }
        }
        if (TBf) {            // opB(k,j) = B[j*ldb+k]  -> contiguous in k
            int kk = tid & 15, j0 = tid >> 4;
            #pragma unroll
            for (int r = 0; r < 4; r++) {
                int jj = j0 + r * 16;
                Bs[kk][jj] = B[(long)(bn + jj) * p.ldb + k0 + kk];
            }
        } else {              // opB(k,j) = B[k*ldb+j]  -> contiguous in j
            int jj = tid & 63, kk0 = tid >> 6;
            #pragma unroll
            for (int r = 0; r < 4; r++) {
                int kk = kk0 + r * 4;
                Bs[kk][jj] = B[(long)(k0 + kk) * p.ldb + bn + jj];
            }
        }
        __syncthreads();
        #pragma unroll
        for (int kk = 0; kk < 16; kk++) {
            float a[4], b4[4];
            #pragma unroll
            for (int u = 0; u < 4; u++) a[u] = As[kk][(ty << 2) + u];
            #pragma unroll
            for (int v = 0; v < 4; v++) b4[v] = Bs[kk][(tx << 2) + v];
            #pragma unroll
            for (int u = 0; u < 4; u++)
                #pragma unroll
                for (int v = 0; v < 4; v++)
                    acc[u][v] = fmaf(a[u], b4[v], acc[u][v]);
        }
        __syncthreads();
    }
    #pragma unroll
    for (int u = 0; u < 4; u++) {
        int row = bm + (ty << 2) + u;
        float4 outv;
        float* o = (float*)&outv;
        #pragma unroll
        for (int v = 0; v < 4; v++) {
            int col = bn + (tx << 2) + v;
            float val = p.alpha * acc[u][v];
            if (ACCf) val += C[(long)row * p.ldc + col];
            if (p.D)  val += p.dcoef * p.D[(long)bz * p.sD + (long)row * p.ldc + col];
            if (p.addI && row == col) val += 1.0f;
            if (EFf)  val += p.vf[(long)bz * p.sVf + row] *
                             p.noise[(long)bz * p.sNoise + (long)row * 256 + col];
            o[v] = val;
        }
        *(float4*)&C[(long)row * p.ldc + bn + (tx << 2)] = outv;
    }
}

// ---------------- Vf = sqrt(Kff_diag - sum_m A*Kuf) ----------------

__global__ void vf_kernel(const float* __restrict__ Achunk, const float* __restrict__ Kuf,
                          const float* __restrict__ Kff, float* __restrict__ Vf,
                          int f0, int nfc) {
    int s = blockIdx.y;
    int fl = blockIdx.x * 256 + threadIdx.x;
    if (fl >= nfc) return;
    const float* Ab = Achunk + (long)s * M_ * nfc;
    const float* Kb = Kuf + (long)s * M_ * NF_ + f0;
    float acc = 0.f;
    for (int m = 0; m < M_; m++)
        acc += Ab[(long)m * nfc + fl] * Kb[(long)m * NF_ + fl];
    float v = Kff[(long)s * NF_ + f0 + fl] - acc;
    Vf[(long)s * NF_ + f0 + fl] = sqrtf(v);
}

__global__ void ucopy_kernel(const float* __restrict__ U, float* __restrict__ out) {
    int i = blockIdx.x * blockDim.x + threadIdx.x;
    if (i < S_ * M_ * OUT_) {
        int s = i >> 16;
        int rc = i & 65535;
        out[(long)s * ROWS_ * OUT_ + rc] = U[i];
    }
}

// ---------------- host ----------------

extern "C" void kernel_launch(void* const* d_in, const int* in_sizes, int n_in,
                              void* d_out, int out_size, void* d_ws, size_t ws_size,
                              hipStream_t stream) {
    const float* Kuu       = (const float*)d_in[0];
    const float* Kuf       = (const float*)d_in[1];
    const float* Kff       = (const float*)d_in[2];
    const float* Lloc      = (const float*)d_in[3];
    const float* Lscale    = (const float*)d_in[4];
    const float* u_param   = (const float*)d_in[5];
    const float* noise_inv = (const float*)d_in[6];
    const float* noise_L   = (const float*)d_in[7];
    const float* noise_f   = (const float*)d_in[8];
    float* out = (float*)d_out;
    float* ws  = (float*)d_ws;

    long off = 1024;
    float* part   = ws + 16;
    float* Lbuf   = ws + off; off += MM_;
    float* UPt    = ws + off; off += MM_;
    float* UP     = ws + off; off += MM_;
    float* Vf     = ws + off; off += (long)S_ * NF_;
    float* cholK  = ws + off; off += (long)S_ * MM_;
    float* TK     = ws + off; off += (long)S_ * MM_;
    float* KuuL   = ws + off; off += (long)S_ * MM_;
    float* choll  = ws + off; off += (long)S_ * MM_;
    float* Tl     = ws + off; off += (long)S_ * MM_;
    float* KuuInv = ws + off; off += (long)S_ * MM_;
    float* lKlpIi = ws + off; off += (long)S_ * MM_;
    float* Stmp   = ws + off; off += (long)S_ * MM_;
    float* Sigma  = ws + off; off += (long)S_ * MM_;
    float* RHS    = ws + off; off += (long)S_ * MM_;
    float* U      = ws + off; off += (long)S_ * MM_;
    float* Achunk = ws + off;
    long avail = (long)(ws_size / 4) - off;
    int nfc = (int)(avail / ((long)S_ * M_));
    nfc = (nfc / 64) * 64;
    if (nfc > NF_) nfc = NF_;
    if (nfc < 64) nfc = 64;

    dim3 b256(256);

    auto run = [&](const float* A, const float* B, float* C,
                   int Mm, int Nn, int Kk, int lda, int ldb, int ldc,
                   long sA, long sB, long sC,
                   int TAf, int TBf, int ACCf, float alpha,
                   const float* D, long sD, float dcoef, int addI,
                   const float* vfp, long sVf, const float* noisep, long sNoise, int EFf,
                   int batch) {
        GemmParams q;
        q.A = A; q.B = B; q.C = C; q.D = D; q.vf = vfp; q.noise = noisep;
        q.M = Mm; q.N = Nn; q.K = Kk; q.lda = lda; q.ldb = ldb; q.ldc = ldc;
        q.sA = sA; q.sB = sB; q.sC = sC; q.sD = sD;
        q.alpha = alpha; q.dcoef = dcoef; q.addI = addI;
        q.sVf = sVf; q.sNoise = sNoise;
        dim3 g(Nn / 64, Mm / 64, batch);
        if (EFf)                gemm_k<1,0,0,1><<<g, b256, 0, stream>>>(q);
        else if (ACCf)          gemm_k<0,1,1,0><<<g, b256, 0, stream>>>(q);
        else if (TAf && TBf)    gemm_k<1,1,0,0><<<g, b256, 0, stream>>>(q);
        else if (TAf)           gemm_k<1,0,0,0><<<g, b256, 0, stream>>>(q);
        else if (TBf)           gemm_k<0,1,0,0><<<g, b256, 0, stream>>>(q);
        else                    gemm_k<0,0,0,0><<<g, b256, 0, stream>>>(q);
    };

    // scalars
    max1_kernel<<<256, b256, 0, stream>>>(Kuu, S_ * MM_, part);
    max2_kernel<<<1, b256, 0, stream>>>(part, ws);
    prep_kernel<<<1, b256, 0, stream>>>(Lloc, Lscale, ws);
    scaleL_kernel<<<256, b256, 0, stream>>>(Lloc, ws, Lbuf);
    copyjit_kernel<<<4096, b256, 0, stream>>>(Kuu, ws, cholK);

    // KuuL = Kuu @ L
    run(Kuu, Lbuf, KuuL, 256,256,256, 256,256,256, MM_,0,MM_, 0,0,0, 1.f,
        nullptr,0,0.f,0, nullptr,0,nullptr,0,0, S_);
    // lKlpI = L^T @ KuuL + I   (into choll buffer)
    run(Lbuf, KuuL, choll, 256,256,256, 256,256,256, 0,MM_,MM_, 1,0,0, 1.f,
        nullptr,0,0.f,1, nullptr,0,nullptr,0,0, S_);

    chol_kernel<<<32, b256, 0, stream>>>(cholK, choll);
    trinv_kernel<<<dim3(4, 32), b256, 0, stream>>>(cholK, choll, TK, Tl);

    // KuuInv = TK^T @ TK ; lKlpIinv = Tl^T @ Tl
    run(TK, TK, KuuInv, 256,256,256, 256,256,256, MM_,MM_,MM_, 1,0,0, 1.f,
        nullptr,0,0.f,0, nullptr,0,nullptr,0,0, S_);
    run(Tl, Tl, lKlpIi, 256,256,256, 256,256,256, MM_,MM_,MM_, 1,0,0, 1.f,
        nullptr,0,0.f,0, nullptr,0,nullptr,0,0, S_);
    // Stmp = KuuL @ lKlpIinv
    run(KuuL, lKlpIi, Stmp, 256,256,256, 256,256,256, MM_,MM_,MM_, 0,0,0, 1.f,
        nullptr,0,0.f,0, nullptr,0,nullptr,0,0, S_);
    // Sigma = Kuu - Stmp @ KuuL^T
    run(Stmp, KuuL, Sigma, 256,256,256, 256,256,256, MM_,MM_,MM_, 0,1,0, -1.f,
        Kuu,MM_,1.f,0, nullptr,0,nullptr,0,0, S_);

    // UP = L @ (L^T @ u_param^T)   (batch 1)
    run(Lbuf, u_param, UPt, 256,256,256, 256,256,256, 0,0,0, 1,1,0, 1.f,
        nullptr,0,0.f,0, nullptr,0,nullptr,0,0, 1);
    run(Lbuf, UPt, UP, 256,256,256, 256,256,256, 0,0,0, 0,0,0, 1.f,
        nullptr,0,0.f,0, nullptr,0,nullptr,0,0, 1);

    // RHS = TK^T @ noise_inv^T + UP
    run(TK, noise_inv, RHS, 256,256,256, 256,256,256, MM_,MM_,MM_, 1,1,0, 1.f,
        UP,0,1.f,0, nullptr,0,nullptr,0,0, S_);
    // RHS += L @ noise_L^T
    run(Lbuf, noise_L, RHS, 256,256,256, 256,256,256, 0,MM_,MM_, 0,1,1, 1.f,
        nullptr,0,0.f,0, nullptr,0,nullptr,0,0, S_);
    // U = Sigma @ RHS
    run(Sigma, RHS, U, 256,256,256, 256,256,256, MM_,MM_,MM_, 0,0,0, 1.f,
        nullptr,0,0.f,0, nullptr,0,nullptr,0,0, S_);

    ucopy_kernel<<<4096, b256, 0, stream>>>(U, out);

    for (int f0 = 0; f0 < NF_; f0 += nfc) {
        int w = NF_ - f0; if (w > nfc) w = nfc;
        // A = KuuInv @ Kuf[:, f0:f0+w]
        run(KuuInv, Kuf + f0, Achunk, 256, w, 256, 256, NF_, w,
            MM_, (long)M_ * NF_, (long)M_ * w, 0,0,0, 1.f,
            nullptr,0,0.f,0, nullptr,0,nullptr,0,0, S_);
        // sqrt(Vf)
        vf_kernel<<<dim3((w + 255) / 256, S_), b256, 0, stream>>>(Achunk, Kuf, Kff, Vf, f0, w);
        // out_f = A^T @ U + sqrt(Vf)*noise_f
        run(Achunk, U, out + (long)(M_ + f0) * OUT_, w, 256, 256, w, 256, 256,
            (long)M_ * w, MM_, (long)ROWS_ * OUT_, 1,0,0, 1.f,
            nullptr,0,0.f,0, Vf + f0, NF_, noise_f + (long)f0 * OUT_, (long)NF_ * OUT_, 1, S_);
    }
}

// Round 4
// 825.893 us; speedup vs baseline: 4.1444x; 1.5829x over previous
//
#include <hip/hip_runtime.h>
#include <math.h>

#define S_ 16
#define M_ 256
#define NF_ 4096
#define OUT_ 256
#define ROWS_ (M_ + NF_)     // 4352
#define JITTER_ 1e-8f
#define MM_ (M_ * M_)        // 65536

// ---------------- small prep kernels ----------------

__global__ void max1_kernel(const float* __restrict__ x, int n, float* part) {
    __shared__ float red[256];
    int tid = threadIdx.x;
    float m = -3.4e38f;
    for (int i = blockIdx.x * blockDim.x + tid; i < n; i += gridDim.x * blockDim.x)
        m = fmaxf(m, x[i]);
    red[tid] = m; __syncthreads();
    for (int s = 128; s > 0; s >>= 1) {
        if (tid < s) red[tid] = fmaxf(red[tid], red[tid + s]);
        __syncthreads();
    }
    if (tid == 0) part[blockIdx.x] = red[0];
}

__global__ void max2_kernel(const float* part, float* ws) {
    __shared__ float red[256];
    int tid = threadIdx.x;
    red[tid] = part[tid]; __syncthreads();
    for (int s = 128; s > 0; s >>= 1) {
        if (tid < s) red[tid] = fmaxf(red[tid], red[tid + s]);
        __syncthreads();
    }
    if (tid == 0) { ws[0] = red[0]; ws[2] = JITTER_ * red[0]; }
}

__global__ void prep_kernel(const float* __restrict__ Lloc, const float* __restrict__ Lscale, float* ws) {
    __shared__ float red[256];
    int tid = threadIdx.x;
    red[tid] = Lloc[tid * M_ + tid];
    __syncthreads();
    for (int s = 128; s > 0; s >>= 1) {
        if (tid < s) red[tid] += red[tid + s];
        __syncthreads();
    }
    if (tid == 0) {
        float norm = red[0] / (float)M_;
        ws[1] = expf(Lscale[0]) / norm;
    }
}

__global__ void scaleL_kernel(const float* __restrict__ Lloc, const float* __restrict__ ws, float* __restrict__ L) {
    int i = blockIdx.x * blockDim.x + threadIdx.x;
    if (i < MM_) L[i] = Lloc[i] * ws[1];
}

__global__ void copyjit_kernel(const float* __restrict__ Kuu, const float* __restrict__ ws, float* __restrict__ dst) {
    int i = blockIdx.x * blockDim.x + threadIdx.x;
    if (i < S_ * MM_) {
        float v = Kuu[i];
        int r = (i >> 8) & 255;
        int c = i & 255;
        if (r == c) v += ws[2];
        dst[i] = v;
    }
}

// ---------------- batched blocked Cholesky (BK=16) ----------------
// Padded packed lower triangle in LDS (row 4m+t: float4 base (m+1)(2m+t),
// m+1 chunks). Thread t owns row t; its 16-wide panel chunk lives in regs.
// Per panel: (A) diag 16x16 factored by one wave via shuffles, published to
// piv[][]; (B) trailing rows forward-solve in regs vs piv (uniform broadcast
// reads); (C) panel written to panT (transposed) + back to P; (D) rank-16
// trailing update, float4 rows vs wave-uniform float4 panT reads. 3 syncs
// per panel. Output: true Cholesky factor in lower triangle of Ag (a few
// pad elements above the diagonal get garbage; only lower tri is consumed).

__global__ __launch_bounds__(256) void chol_kernel(float* bufA, float* bufB) {
    int blk = blockIdx.x;                       // 0..31
    float* Ag = (blk < S_) ? (bufA + (long)blk * MM_) : (bufB + (long)(blk - S_) * MM_);
    __shared__ float P[33280];                  // 133120 B
    __shared__ float panT[16][256];             // 16 KB, [panel col][global row]
    __shared__ float piv[16][18];               // [j][i<j]=L[k0+j][i]; [j][16]=1/d_j
    float4* P4 = (float4*)P;
    int tid = threadIdx.x;
    int lane = tid & 63, wid = tid >> 6;
    int mg = tid >> 2, tg = tid & 3;
    int b4 = (mg + 1) * (2 * mg + tg);          // float4 base of row tid

    // ---- load lower triangle, wave-cooperative, coalesced ----
    for (int i = wid; i < M_; i += 4) {
        int m = i >> 2, t4 = i & 3;
        int rb4 = (m + 1) * (2 * m + t4);
        if (lane <= m) P4[rb4 + lane] = ((const float4*)Ag)[i * 64 + lane];
    }
    __syncthreads();

    float preg[16];
    for (int p = 0; p < 16; p++) {
        int k0 = p << 4;
        int c0 = k0 >> 2;
        // ---- panel chunk -> registers ----
        #pragma unroll
        for (int r = 0; r < 4; r++) {
            float4 v = make_float4(0.f, 0.f, 0.f, 0.f);
            if (tid >= k0 && c0 + r <= mg) v = P4[b4 + c0 + r];
            preg[4 * r + 0] = v.x; preg[4 * r + 1] = v.y;
            preg[4 * r + 2] = v.z; preg[4 * r + 3] = v.w;
        }
        // ---- (A) diag block: one wave, registers + shuffles ----
        int dw = k0 >> 6;
        int lb = k0 & 63;
        if (wid == dw) {
            int dj = lane - lb;
            bool isdiag = (dj >= 0 && dj < 16);
            float myinv = 0.f;
            #pragma unroll
            for (int j = 0; j < 16; j++) {
                float app = __shfl(preg[j], lb + j, 64);
                float d = sqrtf(app);
                float inv = 1.0f / d;
                if (isdiag) {
                    if (dj == j) { preg[j] = d; myinv = inv; }
                    else if (dj > j) preg[j] *= inv;
                }
                #pragma unroll
                for (int j2 = j + 1; j2 < 16; j2++) {
                    float Lj2 = __shfl(preg[j], lb + j2, 64);
                    if (isdiag && dj >= j2) preg[j2] -= preg[j] * Lj2;
                }
            }
            if (isdiag) {
                #pragma unroll
                for (int i = 0; i < 16; i++) piv[dj][i] = preg[i];
                piv[dj][16] = myinv;
            }
        }
        __syncthreads();
        // ---- (B) trailing rows: forward substitution in registers ----
        if (tid > k0 + 15) {
            float x[16];
            #pragma unroll
            for (int j = 0; j < 16; j++) {
                float acc = preg[j];
                #pragma unroll
                for (int i = 0; i < 16; i++)
                    if (i < j) acc -= x[i] * piv[j][i];
                x[j] = acc * piv[j][16];
            }
            #pragma unroll
            for (int j = 0; j < 16; j++) preg[j] = x[j];
        }
        // ---- (C) publish panel (transposed) + write L back to P ----
        if (tid >= k0) {
            #pragma unroll
            for (int j = 0; j < 16; j++) panT[j][tid] = preg[j];
            #pragma unroll
            for (int r = 0; r < 4; r++) {
                int c = c0 + r;
                if (c <= mg)
                    P4[b4 + c] = make_float4(preg[4 * r], preg[4 * r + 1],
                                             preg[4 * r + 2], preg[4 * r + 3]);
            }
        }
        __syncthreads();
        // ---- (D) rank-16 trailing update ----
        int clo = c0 + 4;
        int chi = (wid << 4) + 15;              // max chunk this wave's rows need
        for (int c = clo; c <= chi; c++) {
            if (tid > k0 + 15 && c <= mg) {
                float4 rv = P4[b4 + c];
                #pragma unroll
                for (int tt = 0; tt < 16; tt++) {
                    float4 pv = *(const float4*)&panT[tt][c << 2];
                    rv.x -= preg[tt] * pv.x;
                    rv.y -= preg[tt] * pv.y;
                    rv.z -= preg[tt] * pv.z;
                    rv.w -= preg[tt] * pv.w;
                }
                P4[b4 + c] = rv;
            }
        }
        __syncthreads();
    }

    // ---- writeback, wave-cooperative, coalesced ----
    for (int i = wid; i < M_; i += 4) {
        int m = i >> 2, t4 = i & 3;
        int rb4 = (m + 1) * (2 * m + t4);
        if (lane <= m) ((float4*)Ag)[i * 64 + lane] = P4[rb4 + lane];
    }
}

// ---------------- batched blocked triangular inverse (BK=16) ----------------
// Solve L X = E for 64 columns per workgroup (columns cb*64..cb*64+63).
// X lives in LDS [256][65]. Per 16-block: stage L panel rows k>=t0 into
// panR[k][20] (global read once), diag 16x16 solve by the owning wave
// (column-per-lane, serial-16 in-thread, no syncs), then rank-16 update of
// trailing rows with wave-uniform float4 panel reads. 3 syncs per block.
// Column-group cb skips blocks p < 4*cb (structurally zero).

__global__ __launch_bounds__(256) void trinv_kernel(const float* bufA, const float* bufB,
                                                    float* TA_, float* TB_) {
    int mat = blockIdx.y;      // 0..31
    int cb  = blockIdx.x;      // 0..3 -> columns cb*64 .. cb*64+63
    const float* Lg = (mat < S_) ? (bufA + (long)mat * MM_) : (bufB + (long)(mat - S_) * MM_);
    float* Tg       = (mat < S_) ? (TA_ + (long)mat * MM_) : (TB_ + (long)(mat - S_) * MM_);
    __shared__ float X[M_ * 65];       // 66,560 B  [k][c]
    __shared__ float panR[M_ * 20];    // 20,480 B  [k][j], stride 20 (16B-aligned rows)
    int tid = threadIdx.x;
    int c = tid & 63, q = tid >> 6;    // wave q owns rows [q*64, q*64+64)
    int jglob = cb * 64 + c;

    for (int idx = tid; idx < M_ * 65; idx += 256) X[idx] = 0.f;
    __syncthreads();
    if (q == 0) X[jglob * 65 + c] = 1.0f;   // identity slice (ordered by next sync)

    int p0 = cb * 4;
    for (int p = p0; p < 16; p++) {
        int t0 = p << 4;
        // ---- stage panel: panR[k][j] = Lg[k][t0+j], rows k >= t0 ----
        int k = t0 + tid;
        if (k < M_) {
            const float4* src = (const float4*)&Lg[(long)k * M_ + t0];
            float4* dst = (float4*)&panR[k * 20];
            dst[0] = src[0]; dst[1] = src[1]; dst[2] = src[2]; dst[3] = src[3];
        }
        __syncthreads();
        // ---- diag 16x16 solve, wave owning rows t0..t0+15, column-per-lane ----
        if (q == (t0 >> 6)) {
            float xr[16];
            #pragma unroll
            for (int j = 0; j < 16; j++) {
                float xv = X[(t0 + j) * 65 + c];
                #pragma unroll
                for (int i = 0; i < 16; i++)
                    if (i < j) xv -= panR[(t0 + j) * 20 + i] * xr[i];
                xv *= (1.0f / panR[(t0 + j) * 20 + j]);
                xr[j] = xv;
                X[(t0 + j) * 65 + c] = xv;
            }
        }
        __syncthreads();
        // ---- rank-16 update of trailing rows in this thread's quarter ----
        int kbeg = q << 6; if (kbeg < t0 + 16) kbeg = t0 + 16;
        int kend = (q << 6) + 64;
        if (kbeg < kend) {
            float xr[16];
            #pragma unroll
            for (int j = 0; j < 16; j++) xr[j] = X[(t0 + j) * 65 + c];
            for (int kk = kbeg; kk < kend; kk++) {
                float rv = X[kk * 65 + c];
                const float4* pr = (const float4*)&panR[kk * 20];
                float4 a = pr[0], b = pr[1], d = pr[2], e = pr[3];
                rv -= a.x * xr[0] + a.y * xr[1] + a.z * xr[2] + a.w * xr[3];
                rv -= b.x * xr[4] + b.y * xr[5] + b.z * xr[6] + b.w * xr[7];
                rv -= d.x * xr[8] + d.y * xr[9] + d.z * xr[10] + d.w * xr[11];
                rv -= e.x * xr[12] + e.y * xr[13] + e.z * xr[14] + e.w * xr[15];
                X[kk * 65 + c] = rv;
            }
        }
        __syncthreads();
    }

    // ---- writeback (includes the structural zeros above the diagonal) ----
    for (int idx = tid; idx < M_ * 64; idx += 256) {
        int k = idx >> 6, cc = idx & 63;
        Tg[(long)k * M_ + cb * 64 + cc] = X[k * 65 + cc];
    }
}

// ---------------- generic tiled fp32 GEMM ----------------
// C = alpha*opA(A)@opB(B) [+ C if ACC] [+ dcoef*D] [+ I if addI]
// [+ vf[row]*noise[row*256+col] if EF]    (vf holds sqrt(Vf))

struct GemmParams {
    const float* A; const float* B; float* C;
    const float* D;
    const float* vf; const float* noise;
    int M, N, K;
    int lda, ldb, ldc;
    long sA, sB, sC, sD;
    float alpha, dcoef;
    int addI;
    long sVf, sNoise;
};

template<int TAf, int TBf, int ACCf, int EFf>
__global__ __launch_bounds__(256) void gemm_k(GemmParams p) {
    int bz = blockIdx.z;
    const float* A = p.A + (long)bz * p.sA;
    const float* B = p.B + (long)bz * p.sB;
    float* C = p.C + (long)bz * p.sC;
    int bm = blockIdx.y * 64, bn = blockIdx.x * 64;
    __shared__ float As[16][68];
    __shared__ float Bs[16][68];
    int tid = threadIdx.x;
    int tx = tid & 15, ty = tid >> 4;
    float acc[4][4] = {};
    for (int k0 = 0; k0 < p.K; k0 += 16) {
        if (TAf) {            // opA(i,k) = A[k*lda+i]  -> contiguous in i
            int i = tid & 63, kk0 = tid >> 6;
            #pragma unroll
            for (int r = 0; r < 4; r++) {
                int kk = kk0 + r * 4;
                As[kk][i] = A[(long)(k0 + kk) * p.lda + bm + i];
            }
        } else {              // opA(i,k) = A[i*lda+k]  -> contiguous in k
            int kk = tid & 15, i0 = tid >> 4;
            #pragma unroll
            for (int r = 0; r < 4; r++) {
                int i = i0 + r * 16;
                As[kk][i] = A[(long)(bm + i) * p.lda + k0 + kk];
            }
        }
        if (TBf) {            // opB(k,j) = B[j*ldb+k]  -> contiguous in k
            int kk = tid & 15, j0 = tid >> 4;
            #pragma unroll
            for (int r = 0; r < 4; r++) {
                int jj = j0 + r * 16;
                Bs[kk][jj] = B[(long)(bn + jj) * p.ldb + k0 + kk];
            }
        } else {              // opB(k,j) = B[k*ldb+j]  -> contiguous in j
            int jj = tid & 63, kk0 = tid >> 6;
            #pragma unroll
            for (int r = 0; r < 4; r++) {
                int kk = kk0 + r * 4;
                Bs[kk][jj] = B[(long)(k0 + kk) * p.ldb + bn + jj];
            }
        }
        __syncthreads();
        #pragma unroll
        for (int kk = 0; kk < 16; kk++) {
            float a[4], b4[4];
            #pragma unroll
            for (int u = 0; u < 4; u++) a[u] = As[kk][(ty << 2) + u];
            #pragma unroll
            for (int v = 0; v < 4; v++) b4[v] = Bs[kk][(tx << 2) + v];
            #pragma unroll
            for (int u = 0; u < 4; u++)
                #pragma unroll
                for (int v = 0; v < 4; v++)
                    acc[u][v] = fmaf(a[u], b4[v], acc[u][v]);
        }
        __syncthreads();
    }
    #pragma unroll
    for (int u = 0; u < 4; u++) {
        int row = bm + (ty << 2) + u;
        float4 outv;
        float* o = (float*)&outv;
        #pragma unroll
        for (int v = 0; v < 4; v++) {
            int col = bn + (tx << 2) + v;
            float val = p.alpha * acc[u][v];
            if (ACCf) val += C[(long)row * p.ldc + col];
            if (p.D)  val += p.dcoef * p.D[(long)bz * p.sD + (long)row * p.ldc + col];
            if (p.addI && row == col) val += 1.0f;
            if (EFf)  val += p.vf[(long)bz * p.sVf + row] *
                             p.noise[(long)bz * p.sNoise + (long)row * 256 + col];
            o[v] = val;
        }
        *(float4*)&C[(long)row * p.ldc + bn + (tx << 2)] = outv;
    }
}

// ---------------- Vf = sqrt(Kff_diag - sum_m A*Kuf) ----------------

__global__ void vf_kernel(const float* __restrict__ Achunk, const float* __restrict__ Kuf,
                          const float* __restrict__ Kff, float* __restrict__ Vf,
                          int f0, int nfc) {
    int s = blockIdx.y;
    int fl = blockIdx.x * 256 + threadIdx.x;
    if (fl >= nfc) return;
    const float* Ab = Achunk + (long)s * M_ * nfc;
    const float* Kb = Kuf + (long)s * M_ * NF_ + f0;
    float acc = 0.f;
    for (int m = 0; m < M_; m++)
        acc += Ab[(long)m * nfc + fl] * Kb[(long)m * NF_ + fl];
    float v = Kff[(long)s * NF_ + f0 + fl] - acc;
    Vf[(long)s * NF_ + f0 + fl] = sqrtf(v);
}

__global__ void ucopy_kernel(const float* __restrict__ U, float* __restrict__ out) {
    int i = blockIdx.x * blockDim.x + threadIdx.x;
    if (i < S_ * M_ * OUT_) {
        int s = i >> 16;
        int rc = i & 65535;
        out[(long)s * ROWS_ * OUT_ + rc] = U[i];
    }
}

// ---------------- host ----------------

extern "C" void kernel_launch(void* const* d_in, const int* in_sizes, int n_in,
                              void* d_out, int out_size, void* d_ws, size_t ws_size,
                              hipStream_t stream) {
    const float* Kuu       = (const float*)d_in[0];
    const float* Kuf       = (const float*)d_in[1];
    const float* Kff       = (const float*)d_in[2];
    const float* Lloc      = (const float*)d_in[3];
    const float* Lscale    = (const float*)d_in[4];
    const float* u_param   = (const float*)d_in[5];
    const float* noise_inv = (const float*)d_in[6];
    const float* noise_L   = (const float*)d_in[7];
    const float* noise_f   = (const float*)d_in[8];
    float* out = (float*)d_out;
    float* ws  = (float*)d_ws;

    long off = 1024;
    float* part   = ws + 16;
    float* Lbuf   = ws + off; off += MM_;
    float* UPt    = ws + off; off += MM_;
    float* UP     = ws + off; off += MM_;
    float* Vf     = ws + off; off += (long)S_ * NF_;
    float* cholK  = ws + off; off += (long)S_ * MM_;
    float* TK     = ws + off; off += (long)S_ * MM_;
    float* KuuL   = ws + off; off += (long)S_ * MM_;
    float* choll  = ws + off; off += (long)S_ * MM_;
    float* Tl     = ws + off; off += (long)S_ * MM_;
    float* KuuInv = ws + off; off += (long)S_ * MM_;
    float* lKlpIi = ws + off; off += (long)S_ * MM_;
    float* Stmp   = ws + off; off += (long)S_ * MM_;
    float* Sigma  = ws + off; off += (long)S_ * MM_;
    float* RHS    = ws + off; off += (long)S_ * MM_;
    float* U      = ws + off; off += (long)S_ * MM_;
    float* Achunk = ws + off;
    long avail = (long)(ws_size / 4) - off;
    int nfc = (int)(avail / ((long)S_ * M_));
    nfc = (nfc / 64) * 64;
    if (nfc > NF_) nfc = NF_;
    if (nfc < 64) nfc = 64;

    dim3 b256(256);

    auto run = [&](const float* A, const float* B, float* C,
                   int Mm, int Nn, int Kk, int lda, int ldb, int ldc,
                   long sA, long sB, long sC,
                   int TAf, int TBf, int ACCf, float alpha,
                   const float* D, long sD, float dcoef, int addI,
                   const float* vfp, long sVf, const float* noisep, long sNoise, int EFf,
                   int batch) {
        GemmParams q;
        q.A = A; q.B = B; q.C = C; q.D = D; q.vf = vfp; q.noise = noisep;
        q.M = Mm; q.N = Nn; q.K = Kk; q.lda = lda; q.ldb = ldb; q.ldc = ldc;
        q.sA = sA; q.sB = sB; q.sC = sC; q.sD = sD;
        q.alpha = alpha; q.dcoef = dcoef; q.addI = addI;
        q.sVf = sVf; q.sNoise = sNoise;
        dim3 g(Nn / 64, Mm / 64, batch);
        if (EFf)                gemm_k<1,0,0,1><<<g, b256, 0, stream>>>(q);
        else if (ACCf)          gemm_k<0,1,1,0><<<g, b256, 0, stream>>>(q);
        else if (TAf && TBf)    gemm_k<1,1,0,0><<<g, b256, 0, stream>>>(q);
        else if (TAf)           gemm_k<1,0,0,0><<<g, b256, 0, stream>>>(q);
        else if (TBf)           gemm_k<0,1,0,0><<<g, b256, 0, stream>>>(q);
        else                    gemm_k<0,0,0,0><<<g, b256, 0, stream>>>(q);
    };

    // scalars
    max1_kernel<<<256, b256, 0, stream>>>(Kuu, S_ * MM_, part);
    max2_kernel<<<1, b256, 0, stream>>>(part, ws);
    prep_kernel<<<1, b256, 0, stream>>>(Lloc, Lscale, ws);
    scaleL_kernel<<<256, b256, 0, stream>>>(Lloc, ws, Lbuf);
    copyjit_kernel<<<4096, b256, 0, stream>>>(Kuu, ws, cholK);

    // KuuL = Kuu @ L
    run(Kuu, Lbuf, KuuL, 256,256,256, 256,256,256, MM_,0,MM_, 0,0,0, 1.f,
        nullptr,0,0.f,0, nullptr,0,nullptr,0,0, S_);
    // lKlpI = L^T @ KuuL + I   (into choll buffer)
    run(Lbuf, KuuL, choll, 256,256,256, 256,256,256, 0,MM_,MM_, 1,0,0, 1.f,
        nullptr,0,0.f,1, nullptr,0,nullptr,0,0, S_);

    chol_kernel<<<32, b256, 0, stream>>>(cholK, choll);
    trinv_kernel<<<dim3(4, 32), b256, 0, stream>>>(cholK, choll, TK, Tl);

    // KuuInv = TK^T @ TK ; lKlpIinv = Tl^T @ Tl
    run(TK, TK, KuuInv, 256,256,256, 256,256,256, MM_,MM_,MM_, 1,0,0, 1.f,
        nullptr,0,0.f,0, nullptr,0,nullptr,0,0, S_);
    run(Tl, Tl, lKlpIi, 256,256,256, 256,256,256, MM_,MM_,MM_, 1,0,0, 1.f,
        nullptr,0,0.f,0, nullptr,0,nullptr,0,0, S_);
    // Stmp = KuuL @ lKlpIinv
    run(KuuL, lKlpIi, Stmp, 256,256,256, 256,256,256, MM_,MM_,MM_, 0,0,0, 1.f,
        nullptr,0,0.f,0, nullptr,0,nullptr,0,0, S_);
    // Sigma = Kuu - Stmp @ KuuL^T
    run(Stmp, KuuL, Sigma, 256,256,256, 256,256,256, MM_,MM_,MM_, 0,1,0, -1.f,
        Kuu,MM_,1.f,0, nullptr,0,nullptr,0,0, S_);

    // UP = L @ (L^T @ u_param^T)   (batch 1)
    run(Lbuf, u_param, UPt, 256,256,256, 256,256,256, 0,0,0, 1,1,0, 1.f,
        nullptr,0,0.f,0, nullptr,0,nullptr,0,0, 1);
    run(Lbuf, UPt, UP, 256,256,256, 256,256,256, 0,0,0, 0,0,0, 1.f,
        nullptr,0,0.f,0, nullptr,0,nullptr,0,0, 1);

    // RHS = TK^T @ noise_inv^T + UP
    run(TK, noise_inv, RHS, 256,256,256, 256,256,256, MM_,MM_,MM_, 1,1,0, 1.f,
        UP,0,1.f,0, nullptr,0,nullptr,0,0, S_);
    // RHS += L @ noise_L^T
    run(Lbuf, noise_L, RHS, 256,256,256, 256,256,256, 0,MM_,MM_, 0,1,1, 1.f,
        nullptr,0,0.f,0, nullptr,0,nullptr,0,0, S_);
    // U = Sigma @ RHS
    run(Sigma, RHS, U, 256,256,256, 256,256,256, MM_,MM_,MM_, 0,0,0, 1.f,
        nullptr,0,0.f,0, nullptr,0,nullptr,0,0, S_);

    ucopy_kernel<<<4096, b256, 0, stream>>>(U, out);

    for (int f0 = 0; f0 < NF_; f0 += nfc) {
        int w = NF_ - f0; if (w > nfc) w = nfc;
        // A = KuuInv @ Kuf[:, f0:f0+w]
        run(KuuInv, Kuf + f0, Achunk, 256, w, 256, 256, NF_, w,
            MM_, (long)M_ * NF_, (long)M_ * w, 0,0,0, 1.f,
            nullptr,0,0.f,0, nullptr,0,nullptr,0,0, S_);
        // sqrt(Vf)
        vf_kernel<<<dim3((w + 255) / 256, S_), b256, 0, stream>>>(Achunk, Kuf, Kff, Vf, f0, w);
        // out_f = A^T @ U + sqrt(Vf)*noise_f
        run(Achunk, U, out + (long)(M_ + f0) * OUT_, w, 256, 256, w, 256, 256,
            (long)M_ * w, MM_, (long)ROWS_ * OUT_, 1,0,0, 1.f,
            nullptr,0,0.f,0, Vf + f0, NF_, noise_f + (long)f0 * OUT_, (long)NF_ * OUT_, 1, S_);
    }
}

// Round 5
// 750.929 us; speedup vs baseline: 4.5582x; 1.0998x over previous
//
#include <hip/hip_runtime.h>
#include <math.h>

#define S_ 16
#define M_ 256
#define NF_ 4096
#define OUT_ 256
#define ROWS_ (M_ + NF_)     // 4352
#define JITTER_ 1e-8f
#define MM_ (M_ * M_)        // 65536

// ---------------- small prep kernels ----------------

__global__ void max1_kernel(const float* __restrict__ x, int n, float* part) {
    __shared__ float red[256];
    int tid = threadIdx.x;
    float m = -3.4e38f;
    for (int i = blockIdx.x * blockDim.x + tid; i < n; i += gridDim.x * blockDim.x)
        m = fmaxf(m, x[i]);
    red[tid] = m; __syncthreads();
    for (int s = 128; s > 0; s >>= 1) {
        if (tid < s) red[tid] = fmaxf(red[tid], red[tid + s]);
        __syncthreads();
    }
    if (tid == 0) part[blockIdx.x] = red[0];
}

__global__ void max2_kernel(const float* part, float* ws) {
    __shared__ float red[256];
    int tid = threadIdx.x;
    red[tid] = part[tid]; __syncthreads();
    for (int s = 128; s > 0; s >>= 1) {
        if (tid < s) red[tid] = fmaxf(red[tid], red[tid + s]);
        __syncthreads();
    }
    if (tid == 0) { ws[0] = red[0]; ws[2] = JITTER_ * red[0]; }
}

__global__ void prep_kernel(const float* __restrict__ Lloc, const float* __restrict__ Lscale, float* ws) {
    __shared__ float red[256];
    int tid = threadIdx.x;
    red[tid] = Lloc[tid * M_ + tid];
    __syncthreads();
    for (int s = 128; s > 0; s >>= 1) {
        if (tid < s) red[tid] += red[tid + s];
        __syncthreads();
    }
    if (tid == 0) {
        float norm = red[0] / (float)M_;
        ws[1] = expf(Lscale[0]) / norm;
    }
}

__global__ void scaleL_kernel(const float* __restrict__ Lloc, const float* __restrict__ ws, float* __restrict__ L) {
    int i = blockIdx.x * blockDim.x + threadIdx.x;
    if (i < MM_) L[i] = Lloc[i] * ws[1];
}

__global__ void copyjit_kernel(const float* __restrict__ Kuu, const float* __restrict__ ws, float* __restrict__ dst) {
    int i = blockIdx.x * blockDim.x + threadIdx.x;
    if (i < S_ * MM_) {
        float v = Kuu[i];
        int r = (i >> 8) & 255;
        int c = i & 255;
        if (r == c) v += ws[2];
        dst[i] = v;
    }
}

// ---------------- batched blocked Cholesky (BK=16, 1024 threads) ----------------
// tid = row*4 + sub. Padded packed lower triangle in LDS (row 4m+t: float4
// base (m+1)(2m+t)). Each row's 16-wide panel chunk is duplicated in the 4
// sub-threads' registers. Wave p holds exactly rows 16p..16p+15 (x4 subs), so
// diag block p is factored by wave p via shuffles with no masking. Trailing
// rank-16 update: sub s handles chunks c0+4+s, step 4 (span/4, 4 waves/SIMD
// TLP). 3 syncs per panel. Output: true chol factor in lower triangle of Ag
// (a few pad elements above the diagonal get garbage; never consumed).

__global__ __launch_bounds__(1024) void chol_kernel(float* bufA, float* bufB) {
    int blk = blockIdx.x;                       // 0..31
    float* Ag = (blk < S_) ? (bufA + (long)blk * MM_) : (bufB + (long)(blk - S_) * MM_);
    __shared__ float P[33280];                  // 133120 B
    __shared__ float panT[16][256];             // 16 KB, [panel col][global row]
    __shared__ float piv[16][18];               // [j][i<j]=L[k0+j][i]; [j][16]=1/d_j
    float4* P4 = (float4*)P;
    int tid = threadIdx.x;                      // 0..1023
    int r = tid >> 2, s = tid & 3;              // row, sub
    int lane = tid & 63, wid = tid >> 6;        // wave w holds rows 16w..16w+15
    int mg = r >> 2, tg = r & 3;
    int b4 = (mg + 1) * (2 * mg + tg);          // float4 base of row r

    // ---- load lower triangle, 16 waves, coalesced ----
    for (int i = wid; i < M_; i += 16) {
        int m = i >> 2, t4 = i & 3;
        int rb4 = (m + 1) * (2 * m + t4);
        if (lane <= m) P4[rb4 + lane] = ((const float4*)Ag)[i * 64 + lane];
    }
    __syncthreads();

    float preg[16];
    for (int p = 0; p < 16; p++) {
        int k0 = p << 4;
        int c0 = p << 2;
        // ---- panel chunk -> registers (4 subs duplicate; broadcast reads) ----
        #pragma unroll
        for (int rr = 0; rr < 4; rr++) {
            float4 v = make_float4(0.f, 0.f, 0.f, 0.f);
            if (r >= k0 && c0 + rr <= mg) v = P4[b4 + c0 + rr];
            preg[4 * rr + 0] = v.x; preg[4 * rr + 1] = v.y;
            preg[4 * rr + 2] = v.z; preg[4 * rr + 3] = v.w;
        }
        // ---- (A) diag block: wave p (rows k0..k0+15 x 4 subs), shuffles ----
        if (wid == p) {
            int dj = lane >> 2;                 // row offset in block
            float myinv = 0.f;
            #pragma unroll
            for (int j = 0; j < 16; j++) {
                float app = __shfl(preg[j], 4 * j, 64);
                float d = sqrtf(app);
                float inv = 1.0f / d;
                if (dj == j) { preg[j] = d; myinv = inv; }
                else if (dj > j) preg[j] *= inv;
                #pragma unroll
                for (int j2 = j + 1; j2 < 16; j2++) {
                    float Lj2 = __shfl(preg[j], 4 * j2, 64);
                    if (dj >= j2) preg[j2] -= preg[j] * Lj2;
                }
            }
            if (s == 0) {
                #pragma unroll
                for (int i = 0; i < 16; i++) piv[dj][i] = preg[i];
                piv[dj][16] = myinv;
            }
        }
        __syncthreads();
        // ---- (B) trailing rows: forward substitution (subs duplicate) ----
        if (r > k0 + 15) {
            float x[16];
            #pragma unroll
            for (int j = 0; j < 16; j++) {
                float acc = preg[j];
                #pragma unroll
                for (int i = 0; i < 16; i++)
                    if (i < j) acc -= x[i] * piv[j][i];
                x[j] = acc * piv[j][16];
            }
            #pragma unroll
            for (int j = 0; j < 16; j++) preg[j] = x[j];
        }
        // ---- (C) publish panel (each sub writes 4 panT cols + 1 chunk) ----
        if (r >= k0) {
            #pragma unroll
            for (int j = 0; j < 4; j++) panT[4 * s + j][r] = preg[4 * s + j];
            int c = c0 + s;
            if (c <= mg)
                P4[b4 + c] = make_float4(preg[4 * s], preg[4 * s + 1],
                                         preg[4 * s + 2], preg[4 * s + 3]);
        }
        __syncthreads();
        // ---- (D) rank-16 trailing update, chunks split across subs ----
        if (r > k0 + 15) {
            for (int c = c0 + 4 + s; c <= mg; c += 4) {
                float4 rv = P4[b4 + c];
                #pragma unroll
                for (int tt = 0; tt < 16; tt++) {
                    float4 pv = *(const float4*)&panT[tt][c << 2];
                    rv.x -= preg[tt] * pv.x;
                    rv.y -= preg[tt] * pv.y;
                    rv.z -= preg[tt] * pv.z;
                    rv.w -= preg[tt] * pv.w;
                }
                P4[b4 + c] = rv;
            }
        }
        __syncthreads();
    }

    // ---- writeback, 16 waves, coalesced ----
    for (int i = wid; i < M_; i += 16) {
        int m = i >> 2, t4 = i & 3;
        int rb4 = (m + 1) * (2 * m + t4);
        if (lane <= m) ((float4*)Ag)[i * 64 + lane] = P4[rb4 + lane];
    }
}

// ---------------- batched blocked triangular inverse (BK=16) ----------------
// Solve L X = E for 64 columns per workgroup (columns cb*64..cb*64+63).
// X lives in LDS [256][65]. Per 16-block: stage L panel rows k>=t0 into
// panR[k][20] (global read once), diag 16x16 solve by the owning wave
// (column-per-lane, serial-16 in-thread, no syncs), then rank-16 update of
// trailing rows with wave-uniform float4 panel reads. 3 syncs per block.
// Column-group cb skips blocks p < 4*cb (structurally zero).

__global__ __launch_bounds__(256) void trinv_kernel(const float* bufA, const float* bufB,
                                                    float* TA_, float* TB_) {
    int mat = blockIdx.y;      // 0..31
    int cb  = blockIdx.x;      // 0..3 -> columns cb*64 .. cb*64+63
    const float* Lg = (mat < S_) ? (bufA + (long)mat * MM_) : (bufB + (long)(mat - S_) * MM_);
    float* Tg       = (mat < S_) ? (TA_ + (long)mat * MM_) : (TB_ + (long)(mat - S_) * MM_);
    __shared__ float X[M_ * 65];       // 66,560 B  [k][c]
    __shared__ float panR[M_ * 20];    // 20,480 B  [k][j], stride 20 (16B-aligned rows)
    int tid = threadIdx.x;
    int c = tid & 63, q = tid >> 6;    // wave q owns rows [q*64, q*64+64)
    int jglob = cb * 64 + c;

    for (int idx = tid; idx < M_ * 65; idx += 256) X[idx] = 0.f;
    __syncthreads();
    if (q == 0) X[jglob * 65 + c] = 1.0f;   // identity slice (ordered by next sync)

    int p0 = cb * 4;
    for (int p = p0; p < 16; p++) {
        int t0 = p << 4;
        // ---- stage panel: panR[k][j] = Lg[k][t0+j], rows k >= t0 ----
        int k = t0 + tid;
        if (k < M_) {
            const float4* src = (const float4*)&Lg[(long)k * M_ + t0];
            float4* dst = (float4*)&panR[k * 20];
            dst[0] = src[0]; dst[1] = src[1]; dst[2] = src[2]; dst[3] = src[3];
        }
        __syncthreads();
        // ---- diag 16x16 solve, wave owning rows t0..t0+15, column-per-lane ----
        if (q == (t0 >> 6)) {
            float xr[16];
            #pragma unroll
            for (int j = 0; j < 16; j++) {
                float xv = X[(t0 + j) * 65 + c];
                #pragma unroll
                for (int i = 0; i < 16; i++)
                    if (i < j) xv -= panR[(t0 + j) * 20 + i] * xr[i];
                xv *= (1.0f / panR[(t0 + j) * 20 + j]);
                xr[j] = xv;
                X[(t0 + j) * 65 + c] = xv;
            }
        }
        __syncthreads();
        // ---- rank-16 update of trailing rows in this thread's quarter ----
        int kbeg = q << 6; if (kbeg < t0 + 16) kbeg = t0 + 16;
        int kend = (q << 6) + 64;
        if (kbeg < kend) {
            float xr[16];
            #pragma unroll
            for (int j = 0; j < 16; j++) xr[j] = X[(t0 + j) * 65 + c];
            for (int kk = kbeg; kk < kend; kk++) {
                float rv = X[kk * 65 + c];
                const float4* pr = (const float4*)&panR[kk * 20];
                float4 a = pr[0], b = pr[1], d = pr[2], e = pr[3];
                rv -= a.x * xr[0] + a.y * xr[1] + a.z * xr[2] + a.w * xr[3];
                rv -= b.x * xr[4] + b.y * xr[5] + b.z * xr[6] + b.w * xr[7];
                rv -= d.x * xr[8] + d.y * xr[9] + d.z * xr[10] + d.w * xr[11];
                rv -= e.x * xr[12] + e.y * xr[13] + e.z * xr[14] + e.w * xr[15];
                X[kk * 65 + c] = rv;
            }
        }
        __syncthreads();
    }

    // ---- writeback (includes the structural zeros above the diagonal) ----
    for (int idx = tid; idx < M_ * 64; idx += 256) {
        int k = idx >> 6, cc = idx & 63;
        Tg[(long)k * M_ + cb * 64 + cc] = X[k * 65 + cc];
    }
}

// ---------------- generic tiled fp32 GEMM ----------------
// C = alpha*opA(A)@opB(B) [+ C if ACC] [+ dcoef*D] [+ I if addI]
// [+ vf[row]*noise[row*256+col] if EF]    (vf holds sqrt(Vf))

struct GemmParams {
    const float* A; const float* B; float* C;
    const float* D;
    const float* vf; const float* noise;
    int M, N, K;
    int lda, ldb, ldc;
    long sA, sB, sC, sD;
    float alpha, dcoef;
    int addI;
    long sVf, sNoise;
};

template<int TAf, int TBf, int ACCf, int EFf>
__global__ __launch_bounds__(256) void gemm_k(GemmParams p) {
    int bz = blockIdx.z;
    const float* A = p.A + (long)bz * p.sA;
    const float* B = p.B + (long)bz * p.sB;
    float* C = p.C + (long)bz * p.sC;
    int bm = blockIdx.y * 64, bn = blockIdx.x * 64;
    __shared__ float As[16][68];
    __shared__ float Bs[16][68];
    int tid = threadIdx.x;
    int tx = tid & 15, ty = tid >> 4;
    float acc[4][4] = {};
    for (int k0 = 0; k0 < p.K; k0 += 16) {
        if (TAf) {            // opA(i,k) = A[k*lda+i]  -> contiguous in i
            int i = tid & 63, kk0 = tid >> 6;
            #pragma unroll
            for (int r = 0; r < 4; r++) {
                int kk = kk0 + r * 4;
                As[kk][i] = A[(long)(k0 + kk) * p.lda + bm + i];
            }
        } else {              // opA(i,k) = A[i*lda+k]  -> contiguous in k
            int kk = tid & 15, i0 = tid >> 4;
            #pragma unroll
            for (int r = 0; r < 4; r++) {
                int i = i0 + r * 16;
                As[kk][i] = A[(long)(bm + i) * p.lda + k0 + kk];
            }
        }
        if (TBf) {            // opB(k,j) = B[j*ldb+k]  -> contiguous in k
            int kk = tid & 15, j0 = tid >> 4;
            #pragma unroll
            for (int r = 0; r < 4; r++) {
                int jj = j0 + r * 16;
                Bs[kk][jj] = B[(long)(bn + jj) * p.ldb + k0 + kk];
            }
        } else {              // opB(k,j) = B[k*ldb+j]  -> contiguous in j
            int jj = tid & 63, kk0 = tid >> 6;
            #pragma unroll
            for (int r = 0; r < 4; r++) {
                int kk = kk0 + r * 4;
                Bs[kk][jj] = B[(long)(k0 + kk) * p.ldb + bn + jj];
            }
        }
        __syncthreads();
        #pragma unroll
        for (int kk = 0; kk < 16; kk++) {
            float a[4], b4[4];
            #pragma unroll
            for (int u = 0; u < 4; u++) a[u] = As[kk][(ty << 2) + u];
            #pragma unroll
            for (int v = 0; v < 4; v++) b4[v] = Bs[kk][(tx << 2) + v];
            #pragma unroll
            for (int u = 0; u < 4; u++)
                #pragma unroll
                for (int v = 0; v < 4; v++)
                    acc[u][v] = fmaf(a[u], b4[v], acc[u][v]);
        }
        __syncthreads();
    }
    #pragma unroll
    for (int u = 0; u < 4; u++) {
        int row = bm + (ty << 2) + u;
        float4 outv;
        float* o = (float*)&outv;
        #pragma unroll
        for (int v = 0; v < 4; v++) {
            int col = bn + (tx << 2) + v;
            float val = p.alpha * acc[u][v];
            if (ACCf) val += C[(long)row * p.ldc + col];
            if (p.D)  val += p.dcoef * p.D[(long)bz * p.sD + (long)row * p.ldc + col];
            if (p.addI && row == col) val += 1.0f;
            if (EFf)  val += p.vf[(long)bz * p.sVf + row] *
                             p.noise[(long)bz * p.sNoise + (long)row * 256 + col];
            o[v] = val;
        }
        *(float4*)&C[(long)row * p.ldc + bn + (tx << 2)] = outv;
    }
}

// ---------------- Vf = sqrt(Kff_diag - sum_m A*Kuf) ----------------

__global__ void vf_kernel(const float* __restrict__ Achunk, const float* __restrict__ Kuf,
                          const float* __restrict__ Kff, float* __restrict__ Vf,
                          int f0, int nfc) {
    int s = blockIdx.y;
    int fl = blockIdx.x * 256 + threadIdx.x;
    if (fl >= nfc) return;
    const float* Ab = Achunk + (long)s * M_ * nfc;
    const float* Kb = Kuf + (long)s * M_ * NF_ + f0;
    float acc = 0.f;
    for (int m = 0; m < M_; m++)
        acc += Ab[(long)m * nfc + fl] * Kb[(long)m * NF_ + fl];
    float v = Kff[(long)s * NF_ + f0 + fl] - acc;
    Vf[(long)s * NF_ + f0 + fl] = sqrtf(v);
}

__global__ void ucopy_kernel(const float* __restrict__ U, float* __restrict__ out) {
    int i = blockIdx.x * blockDim.x + threadIdx.x;
    if (i < S_ * M_ * OUT_) {
        int s = i >> 16;
        int rc = i & 65535;
        out[(long)s * ROWS_ * OUT_ + rc] = U[i];
    }
}

// ---------------- host ----------------

extern "C" void kernel_launch(void* const* d_in, const int* in_sizes, int n_in,
                              void* d_out, int out_size, void* d_ws, size_t ws_size,
                              hipStream_t stream) {
    const float* Kuu       = (const float*)d_in[0];
    const float* Kuf       = (const float*)d_in[1];
    const float* Kff       = (const float*)d_in[2];
    const float* Lloc      = (const float*)d_in[3];
    const float* Lscale    = (const float*)d_in[4];
    const float* u_param   = (const float*)d_in[5];
    const float* noise_inv = (const float*)d_in[6];
    const float* noise_L   = (const float*)d_in[7];
    const float* noise_f   = (const float*)d_in[8];
    float* out = (float*)d_out;
    float* ws  = (float*)d_ws;

    long off = 1024;
    float* part   = ws + 16;
    float* Lbuf   = ws + off; off += MM_;
    float* UPt    = ws + off; off += MM_;
    float* UP     = ws + off; off += MM_;
    float* Vf     = ws + off; off += (long)S_ * NF_;
    float* cholK  = ws + off; off += (long)S_ * MM_;
    float* TK     = ws + off; off += (long)S_ * MM_;
    float* KuuL   = ws + off; off += (long)S_ * MM_;
    float* choll  = ws + off; off += (long)S_ * MM_;
    float* Tl     = ws + off; off += (long)S_ * MM_;
    float* KuuInv = ws + off; off += (long)S_ * MM_;
    float* lKlpIi = ws + off; off += (long)S_ * MM_;
    float* Stmp   = ws + off; off += (long)S_ * MM_;
    float* Sigma  = ws + off; off += (long)S_ * MM_;
    float* RHS    = ws + off; off += (long)S_ * MM_;
    float* U      = ws + off; off += (long)S_ * MM_;
    float* Achunk = ws + off;
    long avail = (long)(ws_size / 4) - off;
    int nfc = (int)(avail / ((long)S_ * M_));
    nfc = (nfc / 64) * 64;
    if (nfc > NF_) nfc = NF_;
    if (nfc < 64) nfc = 64;

    dim3 b256(256);

    auto run = [&](const float* A, const float* B, float* C,
                   int Mm, int Nn, int Kk, int lda, int ldb, int ldc,
                   long sA, long sB, long sC,
                   int TAf, int TBf, int ACCf, float alpha,
                   const float* D, long sD, float dcoef, int addI,
                   const float* vfp, long sVf, const float* noisep, long sNoise, int EFf,
                   int batch) {
        GemmParams q;
        q.A = A; q.B = B; q.C = C; q.D = D; q.vf = vfp; q.noise = noisep;
        q.M = Mm; q.N = Nn; q.K = Kk; q.lda = lda; q.ldb = ldb; q.ldc = ldc;
        q.sA = sA; q.sB = sB; q.sC = sC; q.sD = sD;
        q.alpha = alpha; q.dcoef = dcoef; q.addI = addI;
        q.sVf = sVf; q.sNoise = sNoise;
        dim3 g(Nn / 64, Mm / 64, batch);
        if (EFf)                gemm_k<1,0,0,1><<<g, b256, 0, stream>>>(q);
        else if (ACCf)          gemm_k<0,1,1,0><<<g, b256, 0, stream>>>(q);
        else if (TAf && TBf)    gemm_k<1,1,0,0><<<g, b256, 0, stream>>>(q);
        else if (TAf)           gemm_k<1,0,0,0><<<g, b256, 0, stream>>>(q);
        else if (TBf)           gemm_k<0,1,0,0><<<g, b256, 0, stream>>>(q);
        else                    gemm_k<0,0,0,0><<<g, b256, 0, stream>>>(q);
    };

    // scalars
    max1_kernel<<<256, b256, 0, stream>>>(Kuu, S_ * MM_, part);
    max2_kernel<<<1, b256, 0, stream>>>(part, ws);
    prep_kernel<<<1, b256, 0, stream>>>(Lloc, Lscale, ws);
    scaleL_kernel<<<256, b256, 0, stream>>>(Lloc, ws, Lbuf);
    copyjit_kernel<<<4096, b256, 0, stream>>>(Kuu, ws, cholK);

    // KuuL = Kuu @ L
    run(Kuu, Lbuf, KuuL, 256,256,256, 256,256,256, MM_,0,MM_, 0,0,0, 1.f,
        nullptr,0,0.f,0, nullptr,0,nullptr,0,0, S_);
    // lKlpI = L^T @ KuuL + I   (into choll buffer)
    run(Lbuf, KuuL, choll, 256,256,256, 256,256,256, 0,MM_,MM_, 1,0,0, 1.f,
        nullptr,0,0.f,1, nullptr,0,nullptr,0,0, S_);

    chol_kernel<<<32, dim3(1024), 0, stream>>>(cholK, choll);
    trinv_kernel<<<dim3(4, 32), b256, 0, stream>>>(cholK, choll, TK, Tl);

    // KuuInv = TK^T @ TK ; lKlpIinv = Tl^T @ Tl
    run(TK, TK, KuuInv, 256,256,256, 256,256,256, MM_,MM_,MM_, 1,0,0, 1.f,
        nullptr,0,0.f,0, nullptr,0,nullptr,0,0, S_);
    run(Tl, Tl, lKlpIi, 256,256,256, 256,256,256, MM_,MM_,MM_, 1,0,0, 1.f,
        nullptr,0,0.f,0, nullptr,0,nullptr,0,0, S_);
    // Stmp = KuuL @ lKlpIinv
    run(KuuL, lKlpIi, Stmp, 256,256,256, 256,256,256, MM_,MM_,MM_, 0,0,0, 1.f,
        nullptr,0,0.f,0, nullptr,0,nullptr,0,0, S_);
    // Sigma = Kuu - Stmp @ KuuL^T
    run(Stmp, KuuL, Sigma, 256,256,256, 256,256,256, MM_,MM_,MM_, 0,1,0, -1.f,
        Kuu,MM_,1.f,0, nullptr,0,nullptr,0,0, S_);

    // UP = L @ (L^T @ u_param^T)   (batch 1)
    run(Lbuf, u_param, UPt, 256,256,256, 256,256,256, 0,0,0, 1,1,0, 1.f,
        nullptr,0,0.f,0, nullptr,0,nullptr,0,0, 1);
    run(Lbuf, UPt, UP, 256,256,256, 256,256,256, 0,0,0, 0,0,0, 1.f,
        nullptr,0,0.f,0, nullptr,0,nullptr,0,0, 1);

    // RHS = TK^T @ noise_inv^T + UP
    run(TK, noise_inv, RHS, 256,256,256, 256,256,256, MM_,MM_,MM_, 1,1,0, 1.f,
        UP,0,1.f,0, nullptr,0,nullptr,0,0, S_);
    // RHS += L @ noise_L^T
    run(Lbuf, noise_L, RHS, 256,256,256, 256,256,256, 0,MM_,MM_, 0,1,1, 1.f,
        nullptr,0,0.f,0, nullptr,0,nullptr,0,0, S_);
    // U = Sigma @ RHS
    run(Sigma, RHS, U, 256,256,256, 256,256,256, MM_,MM_,MM_, 0,0,0, 1.f,
        nullptr,0,0.f,0, nullptr,0,nullptr,0,0, S_);

    ucopy_kernel<<<4096, b256, 0, stream>>>(U, out);

    for (int f0 = 0; f0 < NF_; f0 += nfc) {
        int w = NF_ - f0; if (w > nfc) w = nfc;
        // A = KuuInv @ Kuf[:, f0:f0+w]
        run(KuuInv, Kuf + f0, Achunk, 256, w, 256, 256, NF_, w,
            MM_, (long)M_ * NF_, (long)M_ * w, 0,0,0, 1.f,
            nullptr,0,0.f,0, nullptr,0,nullptr,0,0, S_);
        // sqrt(Vf)
        vf_kernel<<<dim3((w + 255) / 256, S_), b256, 0, stream>>>(Achunk, Kuf, Kff, Vf, f0, w);
        // out_f = A^T @ U + sqrt(Vf)*noise_f
        run(Achunk, U, out + (long)(M_ + f0) * OUT_, w, 256, 256, w, 256, 256,
            (long)M_ * w, MM_, (long)ROWS_ * OUT_, 1,0,0, 1.f,
            nullptr,0,0.f,0, Vf + f0, NF_, noise_f + (long)f0 * OUT_, (long)NF_ * OUT_, 1, S_);
    }
}